// Round 1
// baseline (7395.921 us; speedup 1.0000x reference)
//
#include <hip/hip_runtime.h>
#include <math.h>

#define L 4096
#define DIN 1024
#define DM 512
#define DI 1024
#define DS 16
#define DTR 32

// ---------------- perm table ----------------
__global__ void perm_k(int* __restrict__ perm, const int* __restrict__ ratep) {
    int p = blockIdx.x * blockDim.x + threadIdx.x;
    if (p >= L) return;
    int rate = ratep[0];
    int cum = 0;
    for (int g = 0; g < rate; ++g) {
        int sz = (L - g + rate - 1) / rate;
        if (p < cum + sz) { perm[p] = g + rate * (p - cum); return; }
        cum += sz;
    }
}

// ---------------- generic fp32 GEMM: C = act(A(MxK) * B(NxK)^T + bias) [+C] ----
// ACT: 0 none, 1 relu, 2 softplus, 3 tanh
// Requires M%64==0, N%64==0, K%32==0 (true for all call sites here).
#define BM 64
#define BN 64
#define BKK 32
template<int ACT>
__global__ __launch_bounds__(256) void gemm_nt(
    const float* __restrict__ A, int lda,
    const float* __restrict__ B, int ldb,
    float* __restrict__ C, int ldc,
    const float* __restrict__ bias,
    int M, int N, int K, int accum)
{
    __shared__ float As[BKK][BM + 4];
    __shared__ float Bs[BKK][BN + 4];
    int tid = threadIdx.x;
    int m0 = blockIdx.y * BM;
    int n0 = blockIdx.x * BN;
    int tx = tid & 15, ty = tid >> 4;
    float acc[4][4] = {};
    int arow = tid >> 3;       // 0..31
    int ak = (tid & 7) * 4;    // 0..28

    for (int k0 = 0; k0 < K; k0 += BKK) {
#pragma unroll
        for (int r = 0; r < 2; ++r) {
            int row = arow + r * 32;
            float4 va = *(const float4*)(A + (size_t)(m0 + row) * lda + k0 + ak);
            As[ak + 0][row] = va.x; As[ak + 1][row] = va.y;
            As[ak + 2][row] = va.z; As[ak + 3][row] = va.w;
            float4 vb = *(const float4*)(B + (size_t)(n0 + row) * ldb + k0 + ak);
            Bs[ak + 0][row] = vb.x; Bs[ak + 1][row] = vb.y;
            Bs[ak + 2][row] = vb.z; Bs[ak + 3][row] = vb.w;
        }
        __syncthreads();
#pragma unroll
        for (int kk = 0; kk < BKK; ++kk) {
            float4 a4 = *(const float4*)&As[kk][ty * 4];
            float4 b4 = *(const float4*)&Bs[kk][tx * 4];
            float a[4] = {a4.x, a4.y, a4.z, a4.w};
            float b[4] = {b4.x, b4.y, b4.z, b4.w};
#pragma unroll
            for (int i = 0; i < 4; ++i)
#pragma unroll
                for (int j = 0; j < 4; ++j)
                    acc[i][j] = fmaf(a[i], b[j], acc[i][j]);
        }
        __syncthreads();
    }

#pragma unroll
    for (int i = 0; i < 4; ++i) {
        int row = m0 + ty * 4 + i;
        int col = n0 + tx * 4;
        float* cp = C + (size_t)row * ldc + col;
        float v[4];
#pragma unroll
        for (int j = 0; j < 4; ++j) {
            float x = acc[i][j] + (bias ? bias[col + j] : 0.f);
            if (ACT == 1) x = fmaxf(x, 0.f);
            else if (ACT == 2) x = (x > 20.f) ? x : log1pf(expf(x));
            else if (ACT == 3) x = tanhf(x);
            v[j] = x;
        }
        if (accum) {
#pragma unroll
            for (int j = 0; j < 4; ++j) v[j] += cp[j];
        }
#pragma unroll
        for (int j = 0; j < 4; ++j) cp[j] = v[j];
    }
}

// ---------------- layernorm (D=512) ----------------
__global__ __launch_bounds__(256) void layernorm_k(
    const float* __restrict__ x, const float* __restrict__ w,
    const float* __restrict__ b, float* __restrict__ o)
{
    int row = blockIdx.x;
    int tid = threadIdx.x;
    const float* xr = x + (size_t)row * DM;
    float v0 = xr[tid], v1 = xr[tid + 256];
    float s = v0 + v1, ss = v0 * v0 + v1 * v1;
    for (int off = 32; off; off >>= 1) {
        s += __shfl_down(s, off, 64);
        ss += __shfl_down(ss, off, 64);
    }
    __shared__ float sm[4], sm2[4];
    int wave = tid >> 6, lane = tid & 63;
    if (lane == 0) { sm[wave] = s; sm2[wave] = ss; }
    __syncthreads();
    float tot = sm[0] + sm[1] + sm[2] + sm[3];
    float tot2 = sm2[0] + sm2[1] + sm2[2] + sm2[3];
    float mu = tot * (1.f / DM);
    float var = tot2 * (1.f / DM) - mu * mu;
    float rs = rsqrtf(var + 1e-5f);
    o[(size_t)row * DM + tid] = (v0 - mu) * rs * w[tid] + b[tid];
    o[(size_t)row * DM + tid + 256] = (v1 - mu) * rs * w[tid + 256] + b[tid + 256];
}

// ---------------- permuted causal conv (K=4) + SiLU ----------------
__global__ __launch_bounds__(256) void conv_silu_k(
    const float* __restrict__ xz, const int* __restrict__ perm,
    const float* __restrict__ cw, const float* __restrict__ cb,
    float* __restrict__ xc)
{
    int g = blockIdx.x * 256 + threadIdx.x;   // g < L*DI
    int c = g & (DI - 1), p = g >> 10;
    float acc = cb[c];
#pragma unroll
    for (int k = 0; k < 4; ++k) {
        int q = p + k - 3;
        if (q >= 0)
            acc = fmaf(xz[(size_t)perm[q] * (2 * DI) + c], cw[c * 4 + k], acc);
    }
    float sig = 1.f / (1.f + __expf(-acc));
    xc[g] = acc * sig;
}

// ---------------- selective scan ----------------
// 64 blocks x 256 threads: thread = (channel_local, state); block = 16 channels.
__global__ __launch_bounds__(256) void scan_k(
    const float* __restrict__ dt, const float* __restrict__ u,
    const float* __restrict__ dbl, const float* __restrict__ xz,
    const float* __restrict__ A_log, const float* __restrict__ Dsk,
    const int* __restrict__ perm, float* __restrict__ yo)
{
    int tid = threadIdx.x;
    int s = tid & 15, cl = tid >> 4;
    int c = blockIdx.x * 16 + cl;
    float Ac = -__expf(A_log[c * DS + s]);
    float Dp = Dsk[c];
    float h = 0.f;
    for (int t = 0; t < L; ++t) {
        float dtv = dt[(size_t)t * DI + c];
        float uv = u[(size_t)t * DI + c];
        float Bv = dbl[(size_t)t * 64 + DTR + s];
        float Cv = dbl[(size_t)t * 64 + DTR + DS + s];
        float dA = __expf(dtv * Ac);
        h = fmaf(dA, h, dtv * uv * Bv);
        float y = h * Cv;
        y += __shfl_xor(y, 1, 64);
        y += __shfl_xor(y, 2, 64);
        y += __shfl_xor(y, 4, 64);
        y += __shfl_xor(y, 8, 64);
        if (s == 0) {
            int tp = perm[t];
            float z = xz[(size_t)tp * (2 * DI) + DI + c];
            float sig = 1.f / (1.f + __expf(-z));
            yo[(size_t)tp * DI + c] = (y + uv * Dp) * (z * sig);
        }
    }
}

// ---------------- attention score: avec[t] = t1[t,:] . w2 + b2 ----------------
__global__ __launch_bounds__(256) void attnscore_k(
    const float* __restrict__ t1, const float* __restrict__ w2,
    const float* __restrict__ b2, float* __restrict__ avec)
{
    int t = blockIdx.x * 256 + threadIdx.x;
    const float* r = t1 + (size_t)t * 128;
    float acc = 0.f;
#pragma unroll 8
    for (int j = 0; j < 128; ++j) acc = fmaf(r[j], w2[j], acc);
    avec[t] = acc + b2[0];
}

// ---------------- softmax over 4096 (single block) ----------------
__global__ __launch_bounds__(1024) void softmax_k(
    const float* __restrict__ a, float* __restrict__ out)
{
    int tid = threadIdx.x;
    float v[4];
    float mx = -1e30f;
#pragma unroll
    for (int i = 0; i < 4; ++i) { v[i] = a[tid + i * 1024]; mx = fmaxf(mx, v[i]); }
    __shared__ float sm[16];
    for (int off = 32; off; off >>= 1) mx = fmaxf(mx, __shfl_xor(mx, off, 64));
    int wave = tid >> 6, lane = tid & 63;
    if (lane == 0) sm[wave] = mx;
    __syncthreads();
    if (tid < 16) {
        float m = sm[tid];
        for (int off = 8; off; off >>= 1) m = fmaxf(m, __shfl_xor(m, off, 64));
        sm[tid] = m;
    }
    __syncthreads();
    mx = sm[0];
    float s = 0.f;
#pragma unroll
    for (int i = 0; i < 4; ++i) { v[i] = __expf(v[i] - mx); s += v[i]; }
    for (int off = 32; off; off >>= 1) s += __shfl_xor(s, off, 64);
    __syncthreads();
    if (lane == 0) sm[wave] = s;
    __syncthreads();
    if (tid < 16) {
        float t2 = sm[tid];
        for (int off = 8; off; off >>= 1) t2 += __shfl_xor(t2, off, 64);
        sm[tid] = t2;
    }
    __syncthreads();
    float inv = 1.f / sm[0];
#pragma unroll
    for (int i = 0; i < 4; ++i) out[tid + i * 1024] = v[i] * inv;
}

__global__ void zero_k(float* p, int n) {
    int i = blockIdx.x * 256 + threadIdx.x;
    if (i < n) p[i] = 0.f;
}

// pooled[m] += sum_t aatt[t]*h[t,m]; 32 blocks x 512 threads, 128 rows each
__global__ __launch_bounds__(512) void pool_k(
    const float* __restrict__ aatt, const float* __restrict__ h,
    float* __restrict__ pooled)
{
    int m = threadIdx.x;
    int t0 = blockIdx.x * 128;
    float acc = 0.f;
    for (int r = 0; r < 128; ++r) {
        int t = t0 + r;
        acc = fmaf(aatt[t], h[(size_t)t * DM + m], acc);
    }
    atomicAdd(&pooled[m], acc);
}

// out[n] = pooled . w[n,:] + b[n]; one wave per output
__global__ __launch_bounds__(64) void out2048_k(
    const float* __restrict__ pooled, const float* __restrict__ w,
    const float* __restrict__ b, float* __restrict__ out)
{
    int n = blockIdx.x;
    int lane = threadIdx.x;
    const float* wr = w + (size_t)n * DM;
    float acc = 0.f;
#pragma unroll
    for (int k = 0; k < 8; ++k)
        acc = fmaf(wr[lane + k * 64], pooled[lane + k * 64], acc);
    for (int off = 32; off; off >>= 1) acc += __shfl_xor(acc, off, 64);
    if (lane == 0) out[n] = acc + b[n];
}

extern "C" void kernel_launch(void* const* d_in, const int* in_sizes, int n_in,
                              void* d_out, int out_size, void* d_ws, size_t ws_size,
                              hipStream_t stream) {
    const float* x     = (const float*)d_in[0];
    const int*   rate  = (const int*)d_in[1];
    const float* fc1_w = (const float*)d_in[2];
    const float* fc1_b = (const float*)d_in[3];
    const float* ln_w  = (const float*)d_in[4];
    const float* ln_b  = (const float*)d_in[5];
    const float* ipw   = (const float*)d_in[6];
    const float* cw    = (const float*)d_in[7];
    const float* cb    = (const float*)d_in[8];
    const float* xpw   = (const float*)d_in[9];
    const float* dtw   = (const float*)d_in[10];
    const float* dtpb  = (const float*)d_in[11];
    const float* A_log = (const float*)d_in[12];
    const float* Dsk   = (const float*)d_in[13];
    const float* opw   = (const float*)d_in[14];
    const float* nw    = (const float*)d_in[15];
    const float* nb    = (const float*)d_in[16];
    const float* aw1   = (const float*)d_in[17];
    const float* ab1   = (const float*)d_in[18];
    const float* aw2   = (const float*)d_in[19];
    const float* ab2   = (const float*)d_in[20];
    const float* ow    = (const float*)d_in[21];
    const float* ob    = (const float*)d_in[22];
    float* out = (float*)d_out;

    int* perm = (int*)d_ws;
    float* f = (float*)d_ws + 4096;
    float* h    = f; f += (size_t)L * DM;
    float* hln  = f; f += (size_t)L * DM;
    float* xz   = f; f += (size_t)L * 2 * DI;
    float* xc   = f; f += (size_t)L * DI;
    float* dbl  = f; f += (size_t)L * 64;
    float* dtv  = f; f += (size_t)L * DI;
    float* yo   = f; f += (size_t)L * DI;
    float* t1   = f; f += (size_t)L * 128;
    float* avec = f; f += L;
    float* pooled = f; f += DM;

    perm_k<<<16, 256, 0, stream>>>(perm, rate);

    // h = relu(x @ fc1_w^T + fc1_b)
    gemm_nt<1><<<dim3(DM / 64, L / 64), 256, 0, stream>>>(
        x, DIN, fc1_w, DIN, h, DM, fc1_b, L, DM, DIN, 0);

    for (int l = 0; l < 2; ++l) {
        layernorm_k<<<L, 256, 0, stream>>>(h, ln_w + l * DM, ln_b + l * DM, hln);
        // xz = hln @ in_proj^T
        gemm_nt<0><<<dim3(2 * DI / 64, L / 64), 256, 0, stream>>>(
            hln, DM, ipw + (size_t)l * 2 * DI * DM, DM, xz, 2 * DI, nullptr,
            L, 2 * DI, DM, 0);
        // xc = silu(causal_conv(x_perm))
        conv_silu_k<<<L * DI / 256, 256, 0, stream>>>(
            xz, perm, cw + (size_t)l * DI * 4, cb + (size_t)l * DI, xc);
        // dbl = xc @ x_proj^T  (N=64)
        gemm_nt<0><<<dim3(1, L / 64), 256, 0, stream>>>(
            xc, DI, xpw + (size_t)l * 64 * DI, DI, dbl, 64, nullptr,
            L, 64, DI, 0);
        // dt = softplus(dbl[:, :32] @ dt_proj^T + dtb)
        gemm_nt<2><<<dim3(DI / 64, L / 64), 256, 0, stream>>>(
            dbl, 64, dtw + (size_t)l * DI * DTR, DTR, dtv, DI,
            dtpb + (size_t)l * DI, L, DI, DTR, 0);
        // selective scan (scatter to original order)
        scan_k<<<64, 256, 0, stream>>>(
            dtv, xc, dbl, xz, A_log + (size_t)l * DI * DS, Dsk + (size_t)l * DI,
            perm, yo);
        // h += yo @ out_proj^T
        gemm_nt<0><<<dim3(DM / 64, L / 64), 256, 0, stream>>>(
            yo, DI, opw + (size_t)l * DM * DI, DI, h, DM, nullptr,
            L, DM, DI, 1);
    }

    layernorm_k<<<L, 256, 0, stream>>>(h, nw, nb, hln);
    // t1 = tanh(hln @ aw1^T + ab1)
    gemm_nt<3><<<dim3(128 / 64, L / 64), 256, 0, stream>>>(
        hln, DM, aw1, DM, t1, 128, ab1, L, 128, DM, 0);
    attnscore_k<<<L / 256, 256, 0, stream>>>(t1, aw2, ab2, avec);
    softmax_k<<<1, 1024, 0, stream>>>(avec, out + 2048);
    zero_k<<<2, 256, 0, stream>>>(pooled, DM);
    pool_k<<<32, 512, 0, stream>>>(out + 2048, hln, pooled);
    out2048_k<<<2048, 64, 0, stream>>>(pooled, ow, ob, out);
}

// Round 2
// 1128.298 us; speedup vs baseline: 6.5549x; 6.5549x over previous
//
#include <hip/hip_runtime.h>
#include <math.h>

#define L 4096
#define DIN 1024
#define DM 512
#define DI 1024
#define DS 16
#define DTR 32
#define NCH 32
#define CHK 128   // NCH*CHK == L

// ---------------- perm table ----------------
__global__ void perm_k(int* __restrict__ perm, const int* __restrict__ ratep) {
    int p = blockIdx.x * blockDim.x + threadIdx.x;
    if (p >= L) return;
    int rate = ratep[0];
    int cum = 0;
    for (int g = 0; g < rate; ++g) {
        int sz = (L - g + rate - 1) / rate;
        if (p < cum + sz) { perm[p] = g + rate * (p - cum); return; }
        cum += sz;
    }
}

// ---------------- generic fp32 GEMM: C = act(A(MxK) * B(NxK)^T + bias) [+C] ----
// ACT: 0 none, 1 relu, 2 softplus, 3 tanh
#define BM 64
#define BN 64
#define BKK 32
template<int ACT>
__global__ __launch_bounds__(256) void gemm_nt(
    const float* __restrict__ A, int lda,
    const float* __restrict__ B, int ldb,
    float* __restrict__ C, int ldc,
    const float* __restrict__ bias,
    int M, int N, int K, int accum)
{
    __shared__ float As[BKK][BM + 4];
    __shared__ float Bs[BKK][BN + 4];
    int tid = threadIdx.x;
    int m0 = blockIdx.y * BM;
    int n0 = blockIdx.x * BN;
    int tx = tid & 15, ty = tid >> 4;
    float acc[4][4] = {};
    int arow = tid >> 3;       // 0..31
    int ak = (tid & 7) * 4;    // 0..28

    for (int k0 = 0; k0 < K; k0 += BKK) {
#pragma unroll
        for (int r = 0; r < 2; ++r) {
            int row = arow + r * 32;
            float4 va = *(const float4*)(A + (size_t)(m0 + row) * lda + k0 + ak);
            As[ak + 0][row] = va.x; As[ak + 1][row] = va.y;
            As[ak + 2][row] = va.z; As[ak + 3][row] = va.w;
            float4 vb = *(const float4*)(B + (size_t)(n0 + row) * ldb + k0 + ak);
            Bs[ak + 0][row] = vb.x; Bs[ak + 1][row] = vb.y;
            Bs[ak + 2][row] = vb.z; Bs[ak + 3][row] = vb.w;
        }
        __syncthreads();
#pragma unroll
        for (int kk = 0; kk < BKK; ++kk) {
            float4 a4 = *(const float4*)&As[kk][ty * 4];
            float4 b4 = *(const float4*)&Bs[kk][tx * 4];
            float a[4] = {a4.x, a4.y, a4.z, a4.w};
            float b[4] = {b4.x, b4.y, b4.z, b4.w};
#pragma unroll
            for (int i = 0; i < 4; ++i)
#pragma unroll
                for (int j = 0; j < 4; ++j)
                    acc[i][j] = fmaf(a[i], b[j], acc[i][j]);
        }
        __syncthreads();
    }

#pragma unroll
    for (int i = 0; i < 4; ++i) {
        int row = m0 + ty * 4 + i;
        int col = n0 + tx * 4;
        float* cp = C + (size_t)row * ldc + col;
        float v[4];
#pragma unroll
        for (int j = 0; j < 4; ++j) {
            float x = acc[i][j] + (bias ? bias[col + j] : 0.f);
            if (ACT == 1) x = fmaxf(x, 0.f);
            else if (ACT == 2) x = (x > 20.f) ? x : log1pf(expf(x));
            else if (ACT == 3) x = tanhf(x);
            v[j] = x;
        }
        if (accum) {
#pragma unroll
            for (int j = 0; j < 4; ++j) v[j] += cp[j];
        }
#pragma unroll
        for (int j = 0; j < 4; ++j) cp[j] = v[j];
    }
}

// ---------------- layernorm (D=512) ----------------
__global__ __launch_bounds__(256) void layernorm_k(
    const float* __restrict__ x, const float* __restrict__ w,
    const float* __restrict__ b, float* __restrict__ o)
{
    int row = blockIdx.x;
    int tid = threadIdx.x;
    const float* xr = x + (size_t)row * DM;
    float v0 = xr[tid], v1 = xr[tid + 256];
    float s = v0 + v1, ss = v0 * v0 + v1 * v1;
    for (int off = 32; off; off >>= 1) {
        s += __shfl_down(s, off, 64);
        ss += __shfl_down(ss, off, 64);
    }
    __shared__ float sm[4], sm2[4];
    int wave = tid >> 6, lane = tid & 63;
    if (lane == 0) { sm[wave] = s; sm2[wave] = ss; }
    __syncthreads();
    float tot = sm[0] + sm[1] + sm[2] + sm[3];
    float tot2 = sm2[0] + sm2[1] + sm2[2] + sm2[3];
    float mu = tot * (1.f / DM);
    float var = tot2 * (1.f / DM) - mu * mu;
    float rs = rsqrtf(var + 1e-5f);
    o[(size_t)row * DM + tid] = (v0 - mu) * rs * w[tid] + b[tid];
    o[(size_t)row * DM + tid + 256] = (v1 - mu) * rs * w[tid + 256] + b[tid + 256];
}

// ---------------- permuted causal conv (K=4) + SiLU ----------------
__global__ __launch_bounds__(256) void conv_silu_k(
    const float* __restrict__ xz, const int* __restrict__ perm,
    const float* __restrict__ cw, const float* __restrict__ cb,
    float* __restrict__ xc)
{
    int g = blockIdx.x * 256 + threadIdx.x;   // g < L*DI
    int c = g & (DI - 1), p = g >> 10;
    float acc = cb[c];
#pragma unroll
    for (int k = 0; k < 4; ++k) {
        int q = p + k - 3;
        if (q >= 0)
            acc = fmaf(xz[(size_t)perm[q] * (2 * DI) + c], cw[c * 4 + k], acc);
    }
    float sig = 1.f / (1.f + __expf(-acc));
    xc[g] = acc * sig;
}

// ---------------- chunked parallel selective scan ----------------
// h[t] = dA[t]*h[t-1] + dt[t]*u[t]*B[t]  is a linear recurrence -> chunk-scan.
// Pass 1: per (channel, state, chunk): local scan from 0 + cumulative prod(dA).
__global__ __launch_bounds__(256) void scan_pass1(
    const float* __restrict__ dt, const float* __restrict__ u,
    const float* __restrict__ dbl, const float* __restrict__ A_log,
    float* __restrict__ Aprod, float* __restrict__ carry)
{
    int tid = threadIdx.x;
    int s = tid & 15, cl = tid >> 4;
    int c = blockIdx.x * 16 + cl;
    int j = blockIdx.y;
    float Ac = -__expf(A_log[c * DS + s]);
    float ap = 1.f, h = 0.f;
    int t0 = j * CHK;
    for (int tt = 0; tt < CHK; ++tt) {
        int t = t0 + tt;
        float dtv = dt[(size_t)t * DI + c];
        float uv  = u[(size_t)t * DI + c];
        float Bv  = dbl[(size_t)t * 64 + DTR + s];
        float dA = __expf(dtv * Ac);
        h = fmaf(dA, h, dtv * uv * Bv);
        ap *= dA;
    }
    int idx = j * (DI * DS) + c * DS + s;
    Aprod[idx] = ap;
    carry[idx] = h;
}

// Pass 2: exclusive prefix across chunks per (c,s). H[0]=0; H[j]=Ap[j-1]*H[j-1]+carry[j-1]
__global__ __launch_bounds__(256) void scan_pass2(
    const float* __restrict__ Aprod, const float* __restrict__ carry,
    float* __restrict__ Hin)
{
    int idx = blockIdx.x * 256 + threadIdx.x;  // (c,s) flat, 16384 total
    float H = 0.f;
    Hin[idx] = 0.f;
    for (int j = 1; j < NCH; ++j) {
        H = fmaf(Aprod[(size_t)(j - 1) * (DI * DS) + idx], H,
                 carry[(size_t)(j - 1) * (DI * DS) + idx]);
        Hin[(size_t)j * (DI * DS) + idx] = H;
    }
}

// Pass 3: re-run local scan seeded with Hin; produce gated output (scattered).
__global__ __launch_bounds__(256) void scan_pass3(
    const float* __restrict__ dt, const float* __restrict__ u,
    const float* __restrict__ dbl, const float* __restrict__ xz,
    const float* __restrict__ A_log, const float* __restrict__ Dsk,
    const int* __restrict__ perm, const float* __restrict__ Hin,
    float* __restrict__ yo)
{
    int tid = threadIdx.x;
    int s = tid & 15, cl = tid >> 4;
    int c = blockIdx.x * 16 + cl;
    int j = blockIdx.y;
    float Ac = -__expf(A_log[c * DS + s]);
    float Dp = Dsk[c];
    float h = Hin[(size_t)j * (DI * DS) + c * DS + s];
    int t0 = j * CHK;
    for (int tt = 0; tt < CHK; ++tt) {
        int t = t0 + tt;
        float dtv = dt[(size_t)t * DI + c];
        float uv  = u[(size_t)t * DI + c];
        float Bv  = dbl[(size_t)t * 64 + DTR + s];
        float Cv  = dbl[(size_t)t * 64 + DTR + DS + s];
        float dA = __expf(dtv * Ac);
        h = fmaf(dA, h, dtv * uv * Bv);
        float y = h * Cv;
        y += __shfl_xor(y, 1, 64);
        y += __shfl_xor(y, 2, 64);
        y += __shfl_xor(y, 4, 64);
        y += __shfl_xor(y, 8, 64);
        if (s == 0) {
            int tp = perm[t];
            float z = xz[(size_t)tp * (2 * DI) + DI + c];
            float sig = 1.f / (1.f + __expf(-z));
            yo[(size_t)tp * DI + c] = (y + uv * Dp) * (z * sig);
        }
    }
}

// ---------------- attention score: avec[t] = t1[t,:] . w2 + b2 ----------------
__global__ __launch_bounds__(256) void attnscore_k(
    const float* __restrict__ t1, const float* __restrict__ w2,
    const float* __restrict__ b2, float* __restrict__ avec)
{
    int t = blockIdx.x * 256 + threadIdx.x;
    const float* r = t1 + (size_t)t * 128;
    float acc = 0.f;
#pragma unroll 8
    for (int j = 0; j < 128; ++j) acc = fmaf(r[j], w2[j], acc);
    avec[t] = acc + b2[0];
}

// ---------------- softmax over 4096 (single block) ----------------
__global__ __launch_bounds__(1024) void softmax_k(
    const float* __restrict__ a, float* __restrict__ out)
{
    int tid = threadIdx.x;
    float v[4];
    float mx = -1e30f;
#pragma unroll
    for (int i = 0; i < 4; ++i) { v[i] = a[tid + i * 1024]; mx = fmaxf(mx, v[i]); }
    __shared__ float sm[16];
    for (int off = 32; off; off >>= 1) mx = fmaxf(mx, __shfl_xor(mx, off, 64));
    int wave = tid >> 6, lane = tid & 63;
    if (lane == 0) sm[wave] = mx;
    __syncthreads();
    if (tid < 16) {
        float m = sm[tid];
        for (int off = 8; off; off >>= 1) m = fmaxf(m, __shfl_xor(m, off, 64));
        sm[tid] = m;
    }
    __syncthreads();
    mx = sm[0];
    float s = 0.f;
#pragma unroll
    for (int i = 0; i < 4; ++i) { v[i] = __expf(v[i] - mx); s += v[i]; }
    for (int off = 32; off; off >>= 1) s += __shfl_xor(s, off, 64);
    __syncthreads();
    if (lane == 0) sm[wave] = s;
    __syncthreads();
    if (tid < 16) {
        float t2 = sm[tid];
        for (int off = 8; off; off >>= 1) t2 += __shfl_xor(t2, off, 64);
        sm[tid] = t2;
    }
    __syncthreads();
    float inv = 1.f / sm[0];
#pragma unroll
    for (int i = 0; i < 4; ++i) out[tid + i * 1024] = v[i] * inv;
}

__global__ void zero_k(float* p, int n) {
    int i = blockIdx.x * 256 + threadIdx.x;
    if (i < n) p[i] = 0.f;
}

// pooled[m] += sum_t aatt[t]*h[t,m]; 32 blocks x 512 threads, 128 rows each
__global__ __launch_bounds__(512) void pool_k(
    const float* __restrict__ aatt, const float* __restrict__ h,
    float* __restrict__ pooled)
{
    int m = threadIdx.x;
    int t0 = blockIdx.x * 128;
    float acc = 0.f;
    for (int r = 0; r < 128; ++r) {
        int t = t0 + r;
        acc = fmaf(aatt[t], h[(size_t)t * DM + m], acc);
    }
    atomicAdd(&pooled[m], acc);
}

// out[n] = pooled . w[n,:] + b[n]; one wave per output
__global__ __launch_bounds__(64) void out2048_k(
    const float* __restrict__ pooled, const float* __restrict__ w,
    const float* __restrict__ b, float* __restrict__ out)
{
    int n = blockIdx.x;
    int lane = threadIdx.x;
    const float* wr = w + (size_t)n * DM;
    float acc = 0.f;
#pragma unroll
    for (int k = 0; k < 8; ++k)
        acc = fmaf(wr[lane + k * 64], pooled[lane + k * 64], acc);
    for (int off = 32; off; off >>= 1) acc += __shfl_xor(acc, off, 64);
    if (lane == 0) out[n] = acc + b[n];
}

extern "C" void kernel_launch(void* const* d_in, const int* in_sizes, int n_in,
                              void* d_out, int out_size, void* d_ws, size_t ws_size,
                              hipStream_t stream) {
    const float* x     = (const float*)d_in[0];
    const int*   rate  = (const int*)d_in[1];
    const float* fc1_w = (const float*)d_in[2];
    const float* fc1_b = (const float*)d_in[3];
    const float* ln_w  = (const float*)d_in[4];
    const float* ln_b  = (const float*)d_in[5];
    const float* ipw   = (const float*)d_in[6];
    const float* cw    = (const float*)d_in[7];
    const float* cb    = (const float*)d_in[8];
    const float* xpw   = (const float*)d_in[9];
    const float* dtw   = (const float*)d_in[10];
    const float* dtpb  = (const float*)d_in[11];
    const float* A_log = (const float*)d_in[12];
    const float* Dsk   = (const float*)d_in[13];
    const float* opw   = (const float*)d_in[14];
    const float* nw    = (const float*)d_in[15];
    const float* nb    = (const float*)d_in[16];
    const float* aw1   = (const float*)d_in[17];
    const float* ab1   = (const float*)d_in[18];
    const float* aw2   = (const float*)d_in[19];
    const float* ab2   = (const float*)d_in[20];
    const float* ow    = (const float*)d_in[21];
    const float* ob    = (const float*)d_in[22];
    float* out = (float*)d_out;

    int* perm = (int*)d_ws;
    float* f = (float*)d_ws + 4096;
    float* h    = f; f += (size_t)L * DM;
    float* hln  = f; f += (size_t)L * DM;
    float* xz   = f; f += (size_t)L * 2 * DI;
    float* xc   = f; f += (size_t)L * DI;
    float* dbl  = f; f += (size_t)L * 64;
    float* dtv  = f; f += (size_t)L * DI;
    float* yo   = f; f += (size_t)L * DI;
    float* t1   = f; f += (size_t)L * 128;
    float* avec = f; f += L;
    float* pooled = f; f += DM;
    float* Aprod = f; f += (size_t)NCH * DI * DS;
    float* carry = f; f += (size_t)NCH * DI * DS;
    float* Hin   = f; f += (size_t)NCH * DI * DS;

    perm_k<<<16, 256, 0, stream>>>(perm, rate);

    // h = relu(x @ fc1_w^T + fc1_b)
    gemm_nt<1><<<dim3(DM / 64, L / 64), 256, 0, stream>>>(
        x, DIN, fc1_w, DIN, h, DM, fc1_b, L, DM, DIN, 0);

    for (int l = 0; l < 2; ++l) {
        layernorm_k<<<L, 256, 0, stream>>>(h, ln_w + l * DM, ln_b + l * DM, hln);
        // xz = hln @ in_proj^T
        gemm_nt<0><<<dim3(2 * DI / 64, L / 64), 256, 0, stream>>>(
            hln, DM, ipw + (size_t)l * 2 * DI * DM, DM, xz, 2 * DI, nullptr,
            L, 2 * DI, DM, 0);
        // xc = silu(causal_conv(x_perm))
        conv_silu_k<<<L * DI / 256, 256, 0, stream>>>(
            xz, perm, cw + (size_t)l * DI * 4, cb + (size_t)l * DI, xc);
        // dbl = xc @ x_proj^T  (N=64)
        gemm_nt<0><<<dim3(1, L / 64), 256, 0, stream>>>(
            xc, DI, xpw + (size_t)l * 64 * DI, DI, dbl, 64, nullptr,
            L, 64, DI, 0);
        // dt = softplus(dbl[:, :32] @ dt_proj^T + dtb)
        gemm_nt<2><<<dim3(DI / 64, L / 64), 256, 0, stream>>>(
            dbl, 64, dtw + (size_t)l * DI * DTR, DTR, dtv, DI,
            dtpb + (size_t)l * DI, L, DI, DTR, 0);
        // chunked parallel selective scan
        scan_pass1<<<dim3(DI / 16, NCH), 256, 0, stream>>>(
            dtv, xc, dbl, A_log + (size_t)l * DI * DS, Aprod, carry);
        scan_pass2<<<DI * DS / 256, 256, 0, stream>>>(Aprod, carry, Hin);
        scan_pass3<<<dim3(DI / 16, NCH), 256, 0, stream>>>(
            dtv, xc, dbl, xz, A_log + (size_t)l * DI * DS, Dsk + (size_t)l * DI,
            perm, Hin, yo);
        // h += yo @ out_proj^T
        gemm_nt<0><<<dim3(DM / 64, L / 64), 256, 0, stream>>>(
            yo, DI, opw + (size_t)l * DM * DI, DI, h, DM, nullptr,
            L, DM, DI, 1);
    }

    layernorm_k<<<L, 256, 0, stream>>>(h, nw, nb, hln);
    // t1 = tanh(hln @ aw1^T + ab1)
    gemm_nt<3><<<dim3(128 / 64, L / 64), 256, 0, stream>>>(
        hln, DM, aw1, DM, t1, 128, ab1, L, 128, DM, 0);
    attnscore_k<<<L / 256, 256, 0, stream>>>(t1, aw2, ab2, avec);
    softmax_k<<<1, 1024, 0, stream>>>(avec, out + 2048);
    zero_k<<<2, 256, 0, stream>>>(pooled, DM);
    pool_k<<<32, 512, 0, stream>>>(out + 2048, hln, pooled);
    out2048_k<<<2048, 64, 0, stream>>>(pooled, ow, ob, out);
}

// Round 3
// 874.936 us; speedup vs baseline: 8.4531x; 1.2896x over previous
//
#include <hip/hip_runtime.h>
#include <hip/hip_fp16.h>
#include <math.h>

#define L 4096
#define DIN 1024
#define DM 512
#define DI 1024
#define DS 16
#define DTR 32
#define NCH 32
#define CHK 128   // NCH*CHK == L

typedef _Float16 v8h __attribute__((ext_vector_type(8)));
typedef float v4f __attribute__((ext_vector_type(4)));

// ---------------- perm table ----------------
__global__ void perm_k(int* __restrict__ perm, const int* __restrict__ ratep) {
    int p = blockIdx.x * blockDim.x + threadIdx.x;
    if (p >= L) return;
    int rate = ratep[0];
    int cum = 0;
    for (int g = 0; g < rate; ++g) {
        int sz = (L - g + rate - 1) / rate;
        if (p < cum + sz) { perm[p] = g + rate * (p - cum); return; }
        cum += sz;
    }
}

// ---------------- fp32 -> fp16 convert (n % 1024 == 0) ----------------
__global__ __launch_bounds__(256) void f2h_k(
    const float* __restrict__ in, _Float16* __restrict__ out)
{
    int i = (blockIdx.x * 256 + threadIdx.x) * 4;
    float4 v = *(const float4*)(in + i);
    _Float16 h4[4] = {(_Float16)v.x, (_Float16)v.y, (_Float16)v.z, (_Float16)v.w};
    *(uint2*)(out + i) = *(uint2*)h4;
}

// ---------------- fp16 MFMA GEMM: C = act(A(MxK) * B(NxK)^T + bias) [+C] ------
// 128x128 block tile, 4 waves of 64x64 (4x4 mfma_f32_16x16x32_f16 tiles).
// Requires M%128==0, N%128==0, K%32==0.
template<int ACT>   // 0 none, 1 relu
__global__ __launch_bounds__(256) void hgemm_nt(
    const _Float16* __restrict__ A, int lda,
    const _Float16* __restrict__ B, int ldb,
    float* __restrict__ C, int ldc,
    const float* __restrict__ bias, int K, int accum)
{
    __shared__ _Float16 As[128][40];   // pad 32->40: 2-way bank alias only (free)
    __shared__ _Float16 Bs[128][40];
    int tid = threadIdx.x;
    int m0 = blockIdx.y * 128, n0 = blockIdx.x * 128;
    int lane = tid & 63, wave = tid >> 6;
    int wm = (wave >> 1) * 64, wn = (wave & 1) * 64;
    int quad = lane >> 4, r16 = lane & 15;
    v4f acc[4][4] = {};

    int srow = tid >> 1;            // 0..127
    int scol = (tid & 1) * 16;      // 0 or 16
    const _Float16* Ag = A + (size_t)(m0 + srow) * lda + scol;
    const _Float16* Bg = B + (size_t)(n0 + srow) * ldb + scol;

    for (int k0 = 0; k0 < K; k0 += 32) {
        uint4 a0 = *(const uint4*)(Ag + k0);
        uint4 a1 = *(const uint4*)(Ag + k0 + 8);
        uint4 b0 = *(const uint4*)(Bg + k0);
        uint4 b1 = *(const uint4*)(Bg + k0 + 8);
        __syncthreads();
        *(uint4*)&As[srow][scol] = a0;
        *(uint4*)&As[srow][scol + 8] = a1;
        *(uint4*)&Bs[srow][scol] = b0;
        *(uint4*)&Bs[srow][scol + 8] = b1;
        __syncthreads();
        v8h af[4], bf[4];
#pragma unroll
        for (int i = 0; i < 4; ++i)
            af[i] = *(const v8h*)&As[wm + i * 16 + r16][quad * 8];
#pragma unroll
        for (int j = 0; j < 4; ++j)
            bf[j] = *(const v8h*)&Bs[wn + j * 16 + r16][quad * 8];
#pragma unroll
        for (int i = 0; i < 4; ++i)
#pragma unroll
            for (int j = 0; j < 4; ++j)
                acc[i][j] = __builtin_amdgcn_mfma_f32_16x16x32_f16(
                    af[i], bf[j], acc[i][j], 0, 0, 0);
    }

    // C/D layout: col = lane&15, row = (lane>>4)*4 + reg
#pragma unroll
    for (int i = 0; i < 4; ++i) {
#pragma unroll
        for (int j = 0; j < 4; ++j) {
            int col = n0 + wn + j * 16 + r16;
            int rbase = m0 + wm + i * 16 + quad * 4;
            float bv = bias ? bias[col] : 0.f;
#pragma unroll
            for (int r = 0; r < 4; ++r) {
                float v = acc[i][j][r] + bv;
                if (ACT == 1) v = fmaxf(v, 0.f);
                float* p = C + (size_t)(rbase + r) * ldc + col;
                if (accum) v += *p;
                *p = v;
            }
        }
    }
}

// ---------------- generic fp32 GEMM (small shapes): C = act(A*B^T + bias) ----
// ACT: 0 none, 2 softplus, 3 tanh
#define BM 64
#define BN 64
#define BKK 32
template<int ACT>
__global__ __launch_bounds__(256) void gemm_nt(
    const float* __restrict__ A, int lda,
    const float* __restrict__ B, int ldb,
    float* __restrict__ C, int ldc,
    const float* __restrict__ bias,
    int M, int N, int K, int accum)
{
    __shared__ float As[BKK][BM + 4];
    __shared__ float Bs[BKK][BN + 4];
    int tid = threadIdx.x;
    int m0 = blockIdx.y * BM;
    int n0 = blockIdx.x * BN;
    int tx = tid & 15, ty = tid >> 4;
    float acc[4][4] = {};
    int arow = tid >> 3;       // 0..31
    int ak = (tid & 7) * 4;    // 0..28

    for (int k0 = 0; k0 < K; k0 += BKK) {
#pragma unroll
        for (int r = 0; r < 2; ++r) {
            int row = arow + r * 32;
            float4 va = *(const float4*)(A + (size_t)(m0 + row) * lda + k0 + ak);
            As[ak + 0][row] = va.x; As[ak + 1][row] = va.y;
            As[ak + 2][row] = va.z; As[ak + 3][row] = va.w;
            float4 vb = *(const float4*)(B + (size_t)(n0 + row) * ldb + k0 + ak);
            Bs[ak + 0][row] = vb.x; Bs[ak + 1][row] = vb.y;
            Bs[ak + 2][row] = vb.z; Bs[ak + 3][row] = vb.w;
        }
        __syncthreads();
#pragma unroll
        for (int kk = 0; kk < BKK; ++kk) {
            float4 a4 = *(const float4*)&As[kk][ty * 4];
            float4 b4 = *(const float4*)&Bs[kk][tx * 4];
            float a[4] = {a4.x, a4.y, a4.z, a4.w};
            float b[4] = {b4.x, b4.y, b4.z, b4.w};
#pragma unroll
            for (int i = 0; i < 4; ++i)
#pragma unroll
                for (int j = 0; j < 4; ++j)
                    acc[i][j] = fmaf(a[i], b[j], acc[i][j]);
        }
        __syncthreads();
    }

#pragma unroll
    for (int i = 0; i < 4; ++i) {
        int row = m0 + ty * 4 + i;
        int col = n0 + tx * 4;
        float* cp = C + (size_t)row * ldc + col;
        float v[4];
#pragma unroll
        for (int j = 0; j < 4; ++j) {
            float x = acc[i][j] + (bias ? bias[col + j] : 0.f);
            if (ACT == 2) x = (x > 20.f) ? x : log1pf(expf(x));
            else if (ACT == 3) x = tanhf(x);
            v[j] = x;
        }
        if (accum) {
#pragma unroll
            for (int j = 0; j < 4; ++j) v[j] += cp[j];
        }
#pragma unroll
        for (int j = 0; j < 4; ++j) cp[j] = v[j];
    }
}

// ---------------- layernorm (D=512), optional fp16 side-output ----------------
__global__ __launch_bounds__(256) void layernorm_k(
    const float* __restrict__ x, const float* __restrict__ w,
    const float* __restrict__ b, float* __restrict__ o,
    _Float16* __restrict__ oh)
{
    int row = blockIdx.x;
    int tid = threadIdx.x;
    const float* xr = x + (size_t)row * DM;
    float v0 = xr[tid], v1 = xr[tid + 256];
    float s = v0 + v1, ss = v0 * v0 + v1 * v1;
    for (int off = 32; off; off >>= 1) {
        s += __shfl_down(s, off, 64);
        ss += __shfl_down(ss, off, 64);
    }
    __shared__ float sm[4], sm2[4];
    int wave = tid >> 6, lane = tid & 63;
    if (lane == 0) { sm[wave] = s; sm2[wave] = ss; }
    __syncthreads();
    float tot = sm[0] + sm[1] + sm[2] + sm[3];
    float tot2 = sm2[0] + sm2[1] + sm2[2] + sm2[3];
    float mu = tot * (1.f / DM);
    float var = tot2 * (1.f / DM) - mu * mu;
    float rs = rsqrtf(var + 1e-5f);
    float y0 = (v0 - mu) * rs * w[tid] + b[tid];
    float y1 = (v1 - mu) * rs * w[tid + 256] + b[tid + 256];
    o[(size_t)row * DM + tid] = y0;
    o[(size_t)row * DM + tid + 256] = y1;
    if (oh) {
        oh[(size_t)row * DM + tid] = (_Float16)y0;
        oh[(size_t)row * DM + tid + 256] = (_Float16)y1;
    }
}

// ---------------- permuted causal conv (K=4) + SiLU ----------------
__global__ __launch_bounds__(256) void conv_silu_k(
    const float* __restrict__ xz, const int* __restrict__ perm,
    const float* __restrict__ cw, const float* __restrict__ cb,
    float* __restrict__ xc)
{
    int g = blockIdx.x * 256 + threadIdx.x;   // g < L*DI
    int c = g & (DI - 1), p = g >> 10;
    float acc = cb[c];
#pragma unroll
    for (int k = 0; k < 4; ++k) {
        int q = p + k - 3;
        if (q >= 0)
            acc = fmaf(xz[(size_t)perm[q] * (2 * DI) + c], cw[c * 4 + k], acc);
    }
    float sig = 1.f / (1.f + __expf(-acc));
    xc[g] = acc * sig;
}

// ---------------- chunked parallel selective scan ----------------
__global__ __launch_bounds__(256) void scan_pass1(
    const float* __restrict__ dt, const float* __restrict__ u,
    const float* __restrict__ dbl, const float* __restrict__ A_log,
    float* __restrict__ Aprod, float* __restrict__ carry)
{
    int tid = threadIdx.x;
    int s = tid & 15, cl = tid >> 4;
    int c = blockIdx.x * 16 + cl;
    int j = blockIdx.y;
    float Ac = -__expf(A_log[c * DS + s]);
    float ap = 1.f, h = 0.f;
    int t0 = j * CHK;
    for (int tt = 0; tt < CHK; ++tt) {
        int t = t0 + tt;
        float dtv = dt[(size_t)t * DI + c];
        float uv  = u[(size_t)t * DI + c];
        float Bv  = dbl[(size_t)t * 64 + DTR + s];
        float dA = __expf(dtv * Ac);
        h = fmaf(dA, h, dtv * uv * Bv);
        ap *= dA;
    }
    int idx = j * (DI * DS) + c * DS + s;
    Aprod[idx] = ap;
    carry[idx] = h;
}

__global__ __launch_bounds__(256) void scan_pass2(
    const float* __restrict__ Aprod, const float* __restrict__ carry,
    float* __restrict__ Hin)
{
    int idx = blockIdx.x * 256 + threadIdx.x;  // (c,s) flat, 16384 total
    float H = 0.f;
    Hin[idx] = 0.f;
    for (int j = 1; j < NCH; ++j) {
        H = fmaf(Aprod[(size_t)(j - 1) * (DI * DS) + idx], H,
                 carry[(size_t)(j - 1) * (DI * DS) + idx]);
        Hin[(size_t)j * (DI * DS) + idx] = H;
    }
}

// Pass 3: seeded local scan; gated output scattered, written fp16 for out_proj.
__global__ __launch_bounds__(256) void scan_pass3(
    const float* __restrict__ dt, const float* __restrict__ u,
    const float* __restrict__ dbl, const float* __restrict__ xz,
    const float* __restrict__ A_log, const float* __restrict__ Dsk,
    const int* __restrict__ perm, const float* __restrict__ Hin,
    _Float16* __restrict__ yo)
{
    int tid = threadIdx.x;
    int s = tid & 15, cl = tid >> 4;
    int c = blockIdx.x * 16 + cl;
    int j = blockIdx.y;
    float Ac = -__expf(A_log[c * DS + s]);
    float Dp = Dsk[c];
    float h = Hin[(size_t)j * (DI * DS) + c * DS + s];
    int t0 = j * CHK;
    for (int tt = 0; tt < CHK; ++tt) {
        int t = t0 + tt;
        float dtv = dt[(size_t)t * DI + c];
        float uv  = u[(size_t)t * DI + c];
        float Bv  = dbl[(size_t)t * 64 + DTR + s];
        float Cv  = dbl[(size_t)t * 64 + DTR + DS + s];
        float dA = __expf(dtv * Ac);
        h = fmaf(dA, h, dtv * uv * Bv);
        float y = h * Cv;
        y += __shfl_xor(y, 1, 64);
        y += __shfl_xor(y, 2, 64);
        y += __shfl_xor(y, 4, 64);
        y += __shfl_xor(y, 8, 64);
        if (s == 0) {
            int tp = perm[t];
            float z = xz[(size_t)tp * (2 * DI) + DI + c];
            float sig = 1.f / (1.f + __expf(-z));
            yo[(size_t)tp * DI + c] = (_Float16)((y + uv * Dp) * (z * sig));
        }
    }
}

// ---------------- attention score: avec[t] = t1[t,:] . w2 + b2 ----------------
__global__ __launch_bounds__(256) void attnscore_k(
    const float* __restrict__ t1, const float* __restrict__ w2,
    const float* __restrict__ b2, float* __restrict__ avec)
{
    int t = blockIdx.x * 256 + threadIdx.x;
    const float* r = t1 + (size_t)t * 128;
    float acc = 0.f;
#pragma unroll 8
    for (int j = 0; j < 128; ++j) acc = fmaf(r[j], w2[j], acc);
    avec[t] = acc + b2[0];
}

// ---------------- softmax over 4096 (single block) ----------------
__global__ __launch_bounds__(1024) void softmax_k(
    const float* __restrict__ a, float* __restrict__ out)
{
    int tid = threadIdx.x;
    float v[4];
    float mx = -1e30f;
#pragma unroll
    for (int i = 0; i < 4; ++i) { v[i] = a[tid + i * 1024]; mx = fmaxf(mx, v[i]); }
    __shared__ float sm[16];
    for (int off = 32; off; off >>= 1) mx = fmaxf(mx, __shfl_xor(mx, off, 64));
    int wave = tid >> 6, lane = tid & 63;
    if (lane == 0) sm[wave] = mx;
    __syncthreads();
    if (tid < 16) {
        float m = sm[tid];
        for (int off = 8; off; off >>= 1) m = fmaxf(m, __shfl_xor(m, off, 64));
        sm[tid] = m;
    }
    __syncthreads();
    mx = sm[0];
    float s = 0.f;
#pragma unroll
    for (int i = 0; i < 4; ++i) { v[i] = __expf(v[i] - mx); s += v[i]; }
    for (int off = 32; off; off >>= 1) s += __shfl_xor(s, off, 64);
    __syncthreads();
    if (lane == 0) sm[wave] = s;
    __syncthreads();
    if (tid < 16) {
        float t2 = sm[tid];
        for (int off = 8; off; off >>= 1) t2 += __shfl_xor(t2, off, 64);
        sm[tid] = t2;
    }
    __syncthreads();
    float inv = 1.f / sm[0];
#pragma unroll
    for (int i = 0; i < 4; ++i) out[tid + i * 1024] = v[i] * inv;
}

__global__ void zero_k(float* p, int n) {
    int i = blockIdx.x * 256 + threadIdx.x;
    if (i < n) p[i] = 0.f;
}

__global__ __launch_bounds__(512) void pool_k(
    const float* __restrict__ aatt, const float* __restrict__ h,
    float* __restrict__ pooled)
{
    int m = threadIdx.x;
    int t0 = blockIdx.x * 128;
    float acc = 0.f;
    for (int r = 0; r < 128; ++r) {
        int t = t0 + r;
        acc = fmaf(aatt[t], h[(size_t)t * DM + m], acc);
    }
    atomicAdd(&pooled[m], acc);
}

__global__ __launch_bounds__(64) void out2048_k(
    const float* __restrict__ pooled, const float* __restrict__ w,
    const float* __restrict__ b, float* __restrict__ out)
{
    int n = blockIdx.x;
    int lane = threadIdx.x;
    const float* wr = w + (size_t)n * DM;
    float acc = 0.f;
#pragma unroll
    for (int k = 0; k < 8; ++k)
        acc = fmaf(wr[lane + k * 64], pooled[lane + k * 64], acc);
    for (int off = 32; off; off >>= 1) acc += __shfl_xor(acc, off, 64);
    if (lane == 0) out[n] = acc + b[n];
}

extern "C" void kernel_launch(void* const* d_in, const int* in_sizes, int n_in,
                              void* d_out, int out_size, void* d_ws, size_t ws_size,
                              hipStream_t stream) {
    const float* x     = (const float*)d_in[0];
    const int*   rate  = (const int*)d_in[1];
    const float* fc1_w = (const float*)d_in[2];
    const float* fc1_b = (const float*)d_in[3];
    const float* ln_w  = (const float*)d_in[4];
    const float* ln_b  = (const float*)d_in[5];
    const float* ipw   = (const float*)d_in[6];
    const float* cw    = (const float*)d_in[7];
    const float* cb    = (const float*)d_in[8];
    const float* xpw   = (const float*)d_in[9];
    const float* dtw   = (const float*)d_in[10];
    const float* dtpb  = (const float*)d_in[11];
    const float* A_log = (const float*)d_in[12];
    const float* Dsk   = (const float*)d_in[13];
    const float* opw   = (const float*)d_in[14];
    const float* nw    = (const float*)d_in[15];
    const float* nb    = (const float*)d_in[16];
    const float* aw1   = (const float*)d_in[17];
    const float* ab1   = (const float*)d_in[18];
    const float* aw2   = (const float*)d_in[19];
    const float* ab2   = (const float*)d_in[20];
    const float* ow    = (const float*)d_in[21];
    const float* ob    = (const float*)d_in[22];
    float* out = (float*)d_out;

    int* perm = (int*)d_ws;
    float* f = (float*)d_ws + 4096;
    float* h    = f; f += (size_t)L * DM;
    float* hln  = f; f += (size_t)L * DM;
    float* xz   = f; f += (size_t)L * 2 * DI;
    float* xc   = f; f += (size_t)L * DI;
    float* dbl  = f; f += (size_t)L * 64;
    float* dtv  = f; f += (size_t)L * DI;
    float* t1   = f; f += (size_t)L * 128;
    float* avec = f; f += L;
    float* pooled = f; f += DM;
    float* Aprod = f; f += (size_t)NCH * DI * DS;
    float* carry = f; f += (size_t)NCH * DI * DS;
    float* Hin   = f; f += (size_t)NCH * DI * DS;
    _Float16* fh = (_Float16*)f;
    _Float16* xh     = fh; fh += (size_t)L * DIN;
    _Float16* hln_h  = fh; fh += (size_t)L * DM;
    _Float16* yo_h   = fh; fh += (size_t)L * DI;
    _Float16* fc1w_h = fh; fh += (size_t)DM * DIN;
    _Float16* ipw_h  = fh; fh += (size_t)2 * 2 * DI * DM;
    _Float16* opw_h  = fh; fh += (size_t)2 * DM * DI;

    perm_k<<<16, 256, 0, stream>>>(perm, rate);

    // weight / input conversions to fp16 (cheap, memory-bound)
    f2h_k<<<L * DIN / 1024, 256, 0, stream>>>(x, xh);
    f2h_k<<<DM * DIN / 1024, 256, 0, stream>>>(fc1_w, fc1w_h);
    f2h_k<<<2 * 2 * DI * DM / 1024, 256, 0, stream>>>(ipw, ipw_h);
    f2h_k<<<2 * DM * DI / 1024, 256, 0, stream>>>(opw, opw_h);

    // h = relu(x @ fc1_w^T + fc1_b)   [fp16 MFMA]
    hgemm_nt<1><<<dim3(DM / 128, L / 128), 256, 0, stream>>>(
        xh, DIN, fc1w_h, DIN, h, DM, fc1_b, DIN, 0);

    for (int l = 0; l < 2; ++l) {
        layernorm_k<<<L, 256, 0, stream>>>(h, ln_w + l * DM, ln_b + l * DM, hln, hln_h);
        // xz = hln @ in_proj^T   [fp16 MFMA]
        hgemm_nt<0><<<dim3(2 * DI / 128, L / 128), 256, 0, stream>>>(
            hln_h, DM, ipw_h + (size_t)l * 2 * DI * DM, DM, xz, 2 * DI,
            nullptr, DM, 0);
        // xc = silu(causal_conv(x_perm))
        conv_silu_k<<<L * DI / 256, 256, 0, stream>>>(
            xz, perm, cw + (size_t)l * DI * 4, cb + (size_t)l * DI, xc);
        // dbl = xc @ x_proj^T  (N=64, fp32 SIMT)
        gemm_nt<0><<<dim3(1, L / 64), 256, 0, stream>>>(
            xc, DI, xpw + (size_t)l * 64 * DI, DI, dbl, 64, nullptr,
            L, 64, DI, 0);
        // dt = softplus(dbl[:, :32] @ dt_proj^T + dtb)  (K=32, fp32 SIMT)
        gemm_nt<2><<<dim3(DI / 64, L / 64), 256, 0, stream>>>(
            dbl, 64, dtw + (size_t)l * DI * DTR, DTR, dtv, DI,
            dtpb + (size_t)l * DI, L, DI, DTR, 0);
        // chunked parallel selective scan
        scan_pass1<<<dim3(DI / 16, NCH), 256, 0, stream>>>(
            dtv, xc, dbl, A_log + (size_t)l * DI * DS, Aprod, carry);
        scan_pass2<<<DI * DS / 256, 256, 0, stream>>>(Aprod, carry, Hin);
        scan_pass3<<<dim3(DI / 16, NCH), 256, 0, stream>>>(
            dtv, xc, dbl, xz, A_log + (size_t)l * DI * DS, Dsk + (size_t)l * DI,
            perm, Hin, yo_h);
        // h += yo @ out_proj^T   [fp16 MFMA, accumulate]
        hgemm_nt<0><<<dim3(DM / 128, L / 128), 256, 0, stream>>>(
            yo_h, DI, opw_h + (size_t)l * DM * DI, DI, h, DM, nullptr, DI, 1);
    }

    layernorm_k<<<L, 256, 0, stream>>>(h, nw, nb, hln, nullptr);
    // t1 = tanh(hln @ aw1^T + ab1)  (fp32 SIMT)
    gemm_nt<3><<<dim3(128 / 64, L / 64), 256, 0, stream>>>(
        hln, DM, aw1, DM, t1, 128, ab1, L, 128, DM, 0);
    attnscore_k<<<L / 256, 256, 0, stream>>>(t1, aw2, ab2, avec);
    softmax_k<<<1, 1024, 0, stream>>>(avec, out + 2048);
    zero_k<<<2, 256, 0, stream>>>(pooled, DM);
    pool_k<<<32, 512, 0, stream>>>(out + 2048, hln, pooled);
    out2048_k<<<2048, 64, 0, stream>>>(pooled, ow, ob, out);
}

// Round 4
// 712.783 us; speedup vs baseline: 10.3761x; 1.2275x over previous
//
#include <hip/hip_runtime.h>
#include <hip/hip_fp16.h>
#include <math.h>

#define L 4096
#define DIN 1024
#define DM 512
#define DI 1024
#define DS 16
#define DTR 32
#define NCH 128
#define CHK 32   // NCH*CHK == L

typedef _Float16 v8h __attribute__((ext_vector_type(8)));
typedef float v4f __attribute__((ext_vector_type(4)));

// ---------------- perm table ----------------
__global__ void perm_k(int* __restrict__ perm, const int* __restrict__ ratep) {
    int p = blockIdx.x * blockDim.x + threadIdx.x;
    if (p >= L) return;
    int rate = ratep[0];
    int cum = 0;
    for (int g = 0; g < rate; ++g) {
        int sz = (L - g + rate - 1) / rate;
        if (p < cum + sz) { perm[p] = g + rate * (p - cum); return; }
        cum += sz;
    }
}

// ---------------- fp32 -> fp16 convert (n % 1024 == 0) ----------------
__global__ __launch_bounds__(256) void f2h_k(
    const float* __restrict__ in, _Float16* __restrict__ out)
{
    int i = (blockIdx.x * 256 + threadIdx.x) * 4;
    float4 v = *(const float4*)(in + i);
    _Float16 h4[4] = {(_Float16)v.x, (_Float16)v.y, (_Float16)v.z, (_Float16)v.w};
    *(uint2*)(out + i) = *(uint2*)h4;
}

// ---------------- fp16 MFMA GEMM: C = act(A(MxK) * B(NxK)^T + bias) [+C] ------
template<int ACT>   // 0 none, 1 relu
__global__ __launch_bounds__(256) void hgemm_nt(
    const _Float16* __restrict__ A, int lda,
    const _Float16* __restrict__ B, int ldb,
    float* __restrict__ C, int ldc,
    const float* __restrict__ bias, int K, int accum)
{
    __shared__ _Float16 As[128][40];   // pad 32->40: 2-way bank alias only (free)
    __shared__ _Float16 Bs[128][40];
    int tid = threadIdx.x;
    int m0 = blockIdx.y * 128, n0 = blockIdx.x * 128;
    int lane = tid & 63, wave = tid >> 6;
    int wm = (wave >> 1) * 64, wn = (wave & 1) * 64;
    int quad = lane >> 4, r16 = lane & 15;
    v4f acc[4][4] = {};

    int srow = tid >> 1;            // 0..127
    int scol = (tid & 1) * 16;      // 0 or 16
    const _Float16* Ag = A + (size_t)(m0 + srow) * lda + scol;
    const _Float16* Bg = B + (size_t)(n0 + srow) * ldb + scol;

    for (int k0 = 0; k0 < K; k0 += 32) {
        uint4 a0 = *(const uint4*)(Ag + k0);
        uint4 a1 = *(const uint4*)(Ag + k0 + 8);
        uint4 b0 = *(const uint4*)(Bg + k0);
        uint4 b1 = *(const uint4*)(Bg + k0 + 8);
        __syncthreads();
        *(uint4*)&As[srow][scol] = a0;
        *(uint4*)&As[srow][scol + 8] = a1;
        *(uint4*)&Bs[srow][scol] = b0;
        *(uint4*)&Bs[srow][scol + 8] = b1;
        __syncthreads();
        v8h af[4], bf[4];
#pragma unroll
        for (int i = 0; i < 4; ++i)
            af[i] = *(const v8h*)&As[wm + i * 16 + r16][quad * 8];
#pragma unroll
        for (int j = 0; j < 4; ++j)
            bf[j] = *(const v8h*)&Bs[wn + j * 16 + r16][quad * 8];
#pragma unroll
        for (int i = 0; i < 4; ++i)
#pragma unroll
            for (int j = 0; j < 4; ++j)
                acc[i][j] = __builtin_amdgcn_mfma_f32_16x16x32_f16(
                    af[i], bf[j], acc[i][j], 0, 0, 0);
    }

    // C/D layout: col = lane&15, row = (lane>>4)*4 + reg
#pragma unroll
    for (int i = 0; i < 4; ++i) {
#pragma unroll
        for (int j = 0; j < 4; ++j) {
            int col = n0 + wn + j * 16 + r16;
            int rbase = m0 + wm + i * 16 + quad * 4;
            float bv = bias ? bias[col] : 0.f;
#pragma unroll
            for (int r = 0; r < 4; ++r) {
                float v = acc[i][j][r] + bv;
                if (ACT == 1) v = fmaxf(v, 0.f);
                float* p = C + (size_t)(rbase + r) * ldc + col;
                if (accum) v += *p;
                *p = v;
            }
        }
    }
}

// ---------------- generic fp32 GEMM (small shapes): C = act(A*B^T + bias) ----
// ACT: 0 none, 2 softplus, 3 tanh
#define BM 64
#define BN 64
#define BKK 32
template<int ACT>
__global__ __launch_bounds__(256) void gemm_nt(
    const float* __restrict__ A, int lda,
    const float* __restrict__ B, int ldb,
    float* __restrict__ C, int ldc,
    const float* __restrict__ bias,
    int M, int N, int K, int accum)
{
    __shared__ float As[BKK][BM + 4];
    __shared__ float Bs[BKK][BN + 4];
    int tid = threadIdx.x;
    int m0 = blockIdx.y * BM;
    int n0 = blockIdx.x * BN;
    int tx = tid & 15, ty = tid >> 4;
    float acc[4][4] = {};
    int arow = tid >> 3;       // 0..31
    int ak = (tid & 7) * 4;    // 0..28

    for (int k0 = 0; k0 < K; k0 += BKK) {
#pragma unroll
        for (int r = 0; r < 2; ++r) {
            int row = arow + r * 32;
            float4 va = *(const float4*)(A + (size_t)(m0 + row) * lda + k0 + ak);
            As[ak + 0][row] = va.x; As[ak + 1][row] = va.y;
            As[ak + 2][row] = va.z; As[ak + 3][row] = va.w;
            float4 vb = *(const float4*)(B + (size_t)(n0 + row) * ldb + k0 + ak);
            Bs[ak + 0][row] = vb.x; Bs[ak + 1][row] = vb.y;
            Bs[ak + 2][row] = vb.z; Bs[ak + 3][row] = vb.w;
        }
        __syncthreads();
#pragma unroll
        for (int kk = 0; kk < BKK; ++kk) {
            float4 a4 = *(const float4*)&As[kk][ty * 4];
            float4 b4 = *(const float4*)&Bs[kk][tx * 4];
            float a[4] = {a4.x, a4.y, a4.z, a4.w};
            float b[4] = {b4.x, b4.y, b4.z, b4.w};
#pragma unroll
            for (int i = 0; i < 4; ++i)
#pragma unroll
                for (int j = 0; j < 4; ++j)
                    acc[i][j] = fmaf(a[i], b[j], acc[i][j]);
        }
        __syncthreads();
    }

#pragma unroll
    for (int i = 0; i < 4; ++i) {
        int row = m0 + ty * 4 + i;
        int col = n0 + tx * 4;
        float* cp = C + (size_t)row * ldc + col;
        float v[4];
#pragma unroll
        for (int j = 0; j < 4; ++j) {
            float x = acc[i][j] + (bias ? bias[col + j] : 0.f);
            if (ACT == 2) x = (x > 20.f) ? x : log1pf(expf(x));
            else if (ACT == 3) x = tanhf(x);
            v[j] = x;
        }
        if (accum) {
#pragma unroll
            for (int j = 0; j < 4; ++j) v[j] += cp[j];
        }
#pragma unroll
        for (int j = 0; j < 4; ++j) cp[j] = v[j];
    }
}

// ---------------- layernorm (D=512), optional fp16 side-output ----------------
__global__ __launch_bounds__(256) void layernorm_k(
    const float* __restrict__ x, const float* __restrict__ w,
    const float* __restrict__ b, float* __restrict__ o,
    _Float16* __restrict__ oh)
{
    int row = blockIdx.x;
    int tid = threadIdx.x;
    const float* xr = x + (size_t)row * DM;
    float v0 = xr[tid], v1 = xr[tid + 256];
    float s = v0 + v1, ss = v0 * v0 + v1 * v1;
    for (int off = 32; off; off >>= 1) {
        s += __shfl_down(s, off, 64);
        ss += __shfl_down(ss, off, 64);
    }
    __shared__ float sm[4], sm2[4];
    int wave = tid >> 6, lane = tid & 63;
    if (lane == 0) { sm[wave] = s; sm2[wave] = ss; }
    __syncthreads();
    float tot = sm[0] + sm[1] + sm[2] + sm[3];
    float tot2 = sm2[0] + sm2[1] + sm2[2] + sm2[3];
    float mu = tot * (1.f / DM);
    float var = tot2 * (1.f / DM) - mu * mu;
    float rs = rsqrtf(var + 1e-5f);
    float y0 = (v0 - mu) * rs * w[tid] + b[tid];
    float y1 = (v1 - mu) * rs * w[tid + 256] + b[tid + 256];
    o[(size_t)row * DM + tid] = y0;
    o[(size_t)row * DM + tid + 256] = y1;
    if (oh) {
        oh[(size_t)row * DM + tid] = (_Float16)y0;
        oh[(size_t)row * DM + tid + 256] = (_Float16)y1;
    }
}

// ---------------- permuted causal conv (K=4) + SiLU ----------------
__global__ __launch_bounds__(256) void conv_silu_k(
    const float* __restrict__ xz, const int* __restrict__ perm,
    const float* __restrict__ cw, const float* __restrict__ cb,
    float* __restrict__ xc)
{
    int g = blockIdx.x * 256 + threadIdx.x;   // g < L*DI
    int c = g & (DI - 1), p = g >> 10;
    float acc = cb[c];
#pragma unroll
    for (int k = 0; k < 4; ++k) {
        int q = p + k - 3;
        if (q >= 0)
            acc = fmaf(xz[(size_t)perm[q] * (2 * DI) + c], cw[c * 4 + k], acc);
    }
    float sig = 1.f / (1.f + __expf(-acc));
    xc[g] = acc * sig;
}

// ---------------- chunked parallel selective scan ----------------
// One thread per (channel, chunk); 16 states in registers. No shuffles, no
// redundant per-state loads; B/C rows broadcast from L1.
__global__ __launch_bounds__(256) void scan_pass1(
    const float* __restrict__ dt, const float* __restrict__ u,
    const float* __restrict__ dbl, const float* __restrict__ A_log,
    float* __restrict__ Aprod, float* __restrict__ carry)
{
    int c = blockIdx.x * 256 + threadIdx.x;
    int j = blockIdx.y;
    float Ac[16];
#pragma unroll
    for (int s = 0; s < 16; ++s) Ac[s] = -__expf(A_log[c * DS + s]);
    float ap[16], h[16];
#pragma unroll
    for (int s = 0; s < 16; ++s) { ap[s] = 1.f; h[s] = 0.f; }
    int t0 = j * CHK;
    for (int tt = 0; tt < CHK; ++tt) {
        int t = t0 + tt;
        float dtv = dt[(size_t)t * DI + c];
        float uv  = u[(size_t)t * DI + c];
        v4f Bv[4];
#pragma unroll
        for (int q = 0; q < 4; ++q)
            Bv[q] = *(const v4f*)(dbl + (size_t)t * 64 + DTR + q * 4);
        float du = dtv * uv;
#pragma unroll
        for (int s = 0; s < 16; ++s) {
            float dA = __expf(dtv * Ac[s]);
            h[s] = fmaf(dA, h[s], du * Bv[s >> 2][s & 3]);
            ap[s] *= dA;
        }
    }
    size_t base = ((size_t)j * DI + c) * DS;
#pragma unroll
    for (int q = 0; q < 4; ++q) {
        *(v4f*)(Aprod + base + q * 4) = *(v4f*)&ap[q * 4];
        *(v4f*)(carry + base + q * 4) = *(v4f*)&h[q * 4];
    }
}

// Pass 2: exclusive prefix across chunks per (c,s).
__global__ __launch_bounds__(256) void scan_pass2(
    const float* __restrict__ Aprod, const float* __restrict__ carry,
    float* __restrict__ Hin)
{
    int idx = blockIdx.x * 256 + threadIdx.x;  // (c,s) flat, 16384 total
    float H = 0.f;
    Hin[idx] = 0.f;
    for (int j = 1; j < NCH; ++j) {
        H = fmaf(Aprod[(size_t)(j - 1) * (DI * DS) + idx], H,
                 carry[(size_t)(j - 1) * (DI * DS) + idx]);
        Hin[(size_t)j * (DI * DS) + idx] = H;
    }
}

// Pass 3: seeded local scan; gated output scattered, written fp16 for out_proj.
__global__ __launch_bounds__(256) void scan_pass3(
    const float* __restrict__ dt, const float* __restrict__ u,
    const float* __restrict__ dbl, const float* __restrict__ xz,
    const float* __restrict__ A_log, const float* __restrict__ Dsk,
    const int* __restrict__ perm, const float* __restrict__ Hin,
    _Float16* __restrict__ yo)
{
    int c = blockIdx.x * 256 + threadIdx.x;
    int j = blockIdx.y;
    float Ac[16];
#pragma unroll
    for (int s = 0; s < 16; ++s) Ac[s] = -__expf(A_log[c * DS + s]);
    float Dp = Dsk[c];
    float h[16];
    size_t hbase = ((size_t)j * DI + c) * DS;
#pragma unroll
    for (int q = 0; q < 4; ++q)
        *(v4f*)&h[q * 4] = *(const v4f*)(Hin + hbase + q * 4);
    int t0 = j * CHK;
    for (int tt = 0; tt < CHK; ++tt) {
        int t = t0 + tt;
        float dtv = dt[(size_t)t * DI + c];
        float uv  = u[(size_t)t * DI + c];
        v4f Bv[4], Cv[4];
#pragma unroll
        for (int q = 0; q < 4; ++q) {
            Bv[q] = *(const v4f*)(dbl + (size_t)t * 64 + DTR + q * 4);
            Cv[q] = *(const v4f*)(dbl + (size_t)t * 64 + DTR + DS + q * 4);
        }
        float du = dtv * uv;
        float y = 0.f;
#pragma unroll
        for (int s = 0; s < 16; ++s) {
            float dA = __expf(dtv * Ac[s]);
            h[s] = fmaf(dA, h[s], du * Bv[s >> 2][s & 3]);
            y = fmaf(h[s], Cv[s >> 2][s & 3], y);
        }
        int tp = perm[t];
        float z = xz[(size_t)tp * (2 * DI) + DI + c];
        float sig = 1.f / (1.f + __expf(-z));
        yo[(size_t)tp * DI + c] = (_Float16)((y + uv * Dp) * (z * sig));
    }
}

// ---------------- attention score: avec[t] = t1[t,:] . w2 + b2 ----------------
__global__ __launch_bounds__(256) void attnscore_k(
    const float* __restrict__ t1, const float* __restrict__ w2,
    const float* __restrict__ b2, float* __restrict__ avec)
{
    int t = blockIdx.x * 256 + threadIdx.x;
    const float* r = t1 + (size_t)t * 128;
    float acc = 0.f;
#pragma unroll 8
    for (int j = 0; j < 128; ++j) acc = fmaf(r[j], w2[j], acc);
    avec[t] = acc + b2[0];
}

// ---------------- softmax over 4096 (single block) ----------------
__global__ __launch_bounds__(1024) void softmax_k(
    const float* __restrict__ a, float* __restrict__ out)
{
    int tid = threadIdx.x;
    float v[4];
    float mx = -1e30f;
#pragma unroll
    for (int i = 0; i < 4; ++i) { v[i] = a[tid + i * 1024]; mx = fmaxf(mx, v[i]); }
    __shared__ float sm[16];
    for (int off = 32; off; off >>= 1) mx = fmaxf(mx, __shfl_xor(mx, off, 64));
    int wave = tid >> 6, lane = tid & 63;
    if (lane == 0) sm[wave] = mx;
    __syncthreads();
    if (tid < 16) {
        float m = sm[tid];
        for (int off = 8; off; off >>= 1) m = fmaxf(m, __shfl_xor(m, off, 64));
        sm[tid] = m;
    }
    __syncthreads();
    mx = sm[0];
    float s = 0.f;
#pragma unroll
    for (int i = 0; i < 4; ++i) { v[i] = __expf(v[i] - mx); s += v[i]; }
    for (int off = 32; off; off >>= 1) s += __shfl_xor(s, off, 64);
    __syncthreads();
    if (lane == 0) sm[wave] = s;
    __syncthreads();
    if (tid < 16) {
        float t2 = sm[tid];
        for (int off = 8; off; off >>= 1) t2 += __shfl_xor(t2, off, 64);
        sm[tid] = t2;
    }
    __syncthreads();
    float inv = 1.f / sm[0];
#pragma unroll
    for (int i = 0; i < 4; ++i) out[tid + i * 1024] = v[i] * inv;
}

__global__ void zero_k(float* p, int n) {
    int i = blockIdx.x * 256 + threadIdx.x;
    if (i < n) p[i] = 0.f;
}

__global__ __launch_bounds__(512) void pool_k(
    const float* __restrict__ aatt, const float* __restrict__ h,
    float* __restrict__ pooled)
{
    int m = threadIdx.x;
    int t0 = blockIdx.x * 128;
    float acc = 0.f;
    for (int r = 0; r < 128; ++r) {
        int t = t0 + r;
        acc = fmaf(aatt[t], h[(size_t)t * DM + m], acc);
    }
    atomicAdd(&pooled[m], acc);
}

__global__ __launch_bounds__(64) void out2048_k(
    const float* __restrict__ pooled, const float* __restrict__ w,
    const float* __restrict__ b, float* __restrict__ out)
{
    int n = blockIdx.x;
    int lane = threadIdx.x;
    const float* wr = w + (size_t)n * DM;
    float acc = 0.f;
#pragma unroll
    for (int k = 0; k < 8; ++k)
        acc = fmaf(wr[lane + k * 64], pooled[lane + k * 64], acc);
    for (int off = 32; off; off >>= 1) acc += __shfl_xor(acc, off, 64);
    if (lane == 0) out[n] = acc + b[n];
}

extern "C" void kernel_launch(void* const* d_in, const int* in_sizes, int n_in,
                              void* d_out, int out_size, void* d_ws, size_t ws_size,
                              hipStream_t stream) {
    const float* x     = (const float*)d_in[0];
    const int*   rate  = (const int*)d_in[1];
    const float* fc1_w = (const float*)d_in[2];
    const float* fc1_b = (const float*)d_in[3];
    const float* ln_w  = (const float*)d_in[4];
    const float* ln_b  = (const float*)d_in[5];
    const float* ipw   = (const float*)d_in[6];
    const float* cw    = (const float*)d_in[7];
    const float* cb    = (const float*)d_in[8];
    const float* xpw   = (const float*)d_in[9];
    const float* dtw   = (const float*)d_in[10];
    const float* dtpb  = (const float*)d_in[11];
    const float* A_log = (const float*)d_in[12];
    const float* Dsk   = (const float*)d_in[13];
    const float* opw   = (const float*)d_in[14];
    const float* nw    = (const float*)d_in[15];
    const float* nb    = (const float*)d_in[16];
    const float* aw1   = (const float*)d_in[17];
    const float* ab1   = (const float*)d_in[18];
    const float* aw2   = (const float*)d_in[19];
    const float* ab2   = (const float*)d_in[20];
    const float* ow    = (const float*)d_in[21];
    const float* ob    = (const float*)d_in[22];
    float* out = (float*)d_out;

    int* perm = (int*)d_ws;
    float* f = (float*)d_ws + 4096;
    float* h    = f; f += (size_t)L * DM;
    float* hln  = f; f += (size_t)L * DM;
    float* xz   = f; f += (size_t)L * 2 * DI;
    float* xc   = f; f += (size_t)L * DI;
    float* dbl  = f; f += (size_t)L * 64;
    float* dtv  = f; f += (size_t)L * DI;
    float* t1   = f; f += (size_t)L * 128;
    float* avec = f; f += L;
    float* pooled = f; f += DM;
    float* Aprod = f; f += (size_t)NCH * DI * DS;
    float* carry = f; f += (size_t)NCH * DI * DS;
    float* Hin   = f; f += (size_t)NCH * DI * DS;
    _Float16* fh = (_Float16*)f;
    _Float16* xh     = fh; fh += (size_t)L * DIN;
    _Float16* hln_h  = fh; fh += (size_t)L * DM;
    _Float16* yo_h   = fh; fh += (size_t)L * DI;
    _Float16* fc1w_h = fh; fh += (size_t)DM * DIN;
    _Float16* ipw_h  = fh; fh += (size_t)2 * 2 * DI * DM;
    _Float16* opw_h  = fh; fh += (size_t)2 * DM * DI;

    perm_k<<<16, 256, 0, stream>>>(perm, rate);

    // weight / input conversions to fp16 (cheap, memory-bound)
    f2h_k<<<L * DIN / 1024, 256, 0, stream>>>(x, xh);
    f2h_k<<<DM * DIN / 1024, 256, 0, stream>>>(fc1_w, fc1w_h);
    f2h_k<<<2 * 2 * DI * DM / 1024, 256, 0, stream>>>(ipw, ipw_h);
    f2h_k<<<2 * DM * DI / 1024, 256, 0, stream>>>(opw, opw_h);

    // h = relu(x @ fc1_w^T + fc1_b)   [fp16 MFMA]
    hgemm_nt<1><<<dim3(DM / 128, L / 128), 256, 0, stream>>>(
        xh, DIN, fc1w_h, DIN, h, DM, fc1_b, DIN, 0);

    for (int l = 0; l < 2; ++l) {
        layernorm_k<<<L, 256, 0, stream>>>(h, ln_w + l * DM, ln_b + l * DM, hln, hln_h);
        // xz = hln @ in_proj^T   [fp16 MFMA]
        hgemm_nt<0><<<dim3(2 * DI / 128, L / 128), 256, 0, stream>>>(
            hln_h, DM, ipw_h + (size_t)l * 2 * DI * DM, DM, xz, 2 * DI,
            nullptr, DM, 0);
        // xc = silu(causal_conv(x_perm))
        conv_silu_k<<<L * DI / 256, 256, 0, stream>>>(
            xz, perm, cw + (size_t)l * DI * 4, cb + (size_t)l * DI, xc);
        // dbl = xc @ x_proj^T  (N=64, fp32 SIMT)
        gemm_nt<0><<<dim3(1, L / 64), 256, 0, stream>>>(
            xc, DI, xpw + (size_t)l * 64 * DI, DI, dbl, 64, nullptr,
            L, 64, DI, 0);
        // dt = softplus(dbl[:, :32] @ dt_proj^T + dtb)  (K=32, fp32 SIMT)
        gemm_nt<2><<<dim3(DI / 64, L / 64), 256, 0, stream>>>(
            dbl, 64, dtw + (size_t)l * DI * DTR, DTR, dtv, DI,
            dtpb + (size_t)l * DI, L, DI, DTR, 0);
        // chunked parallel selective scan (channel-per-thread, states in regs)
        scan_pass1<<<dim3(DI / 256, NCH), 256, 0, stream>>>(
            dtv, xc, dbl, A_log + (size_t)l * DI * DS, Aprod, carry);
        scan_pass2<<<DI * DS / 256, 256, 0, stream>>>(Aprod, carry, Hin);
        scan_pass3<<<dim3(DI / 256, NCH), 256, 0, stream>>>(
            dtv, xc, dbl, xz, A_log + (size_t)l * DI * DS, Dsk + (size_t)l * DI,
            perm, Hin, yo_h);
        // h += yo @ out_proj^T   [fp16 MFMA, accumulate]
        hgemm_nt<0><<<dim3(DM / 128, L / 128), 256, 0, stream>>>(
            yo_h, DI, opw_h + (size_t)l * DM * DI, DI, h, DM, nullptr, DI, 1);
    }

    layernorm_k<<<L, 256, 0, stream>>>(h, nw, nb, hln, nullptr);
    // t1 = tanh(hln @ aw1^T + ab1)  (fp32 SIMT)
    gemm_nt<3><<<dim3(128 / 64, L / 64), 256, 0, stream>>>(
        hln, DM, aw1, DM, t1, 128, ab1, L, 128, DM, 0);
    attnscore_k<<<L / 256, 256, 0, stream>>>(t1, aw2, ab2, avec);
    softmax_k<<<1, 1024, 0, stream>>>(avec, out + 2048);
    zero_k<<<2, 256, 0, stream>>>(pooled, DM);
    pool_k<<<32, 512, 0, stream>>>(out + 2048, hln, pooled);
    out2048_k<<<2048, 64, 0, stream>>>(pooled, ow, ob, out);
}

// Round 5
// 660.136 us; speedup vs baseline: 11.2036x; 1.0798x over previous
//
#include <hip/hip_runtime.h>
#include <hip/hip_fp16.h>
#include <math.h>

#define L 4096
#define DIN 1024
#define DM 512
#define DI 1024
#define DS 16
#define DTR 32
#define NCH 128
#define CHK 32   // NCH*CHK == L

typedef _Float16 v8h __attribute__((ext_vector_type(8)));
typedef float v4f __attribute__((ext_vector_type(4)));

// ---------------- perm table ----------------
__global__ void perm_k(int* __restrict__ perm, const int* __restrict__ ratep) {
    int p = blockIdx.x * blockDim.x + threadIdx.x;
    if (p >= L) return;
    int rate = ratep[0];
    int cum = 0;
    for (int g = 0; g < rate; ++g) {
        int sz = (L - g + rate - 1) / rate;
        if (p < cum + sz) { perm[p] = g + rate * (p - cum); return; }
        cum += sz;
    }
}

// ---------------- fp32 -> fp16 convert (n % 1024 == 0) ----------------
__global__ __launch_bounds__(256) void f2h_k(
    const float* __restrict__ in, _Float16* __restrict__ out)
{
    int i = (blockIdx.x * 256 + threadIdx.x) * 4;
    float4 v = *(const float4*)(in + i);
    _Float16 h4[4] = {(_Float16)v.x, (_Float16)v.y, (_Float16)v.z, (_Float16)v.w};
    *(uint2*)(out + i) = *(uint2*)h4;
}

// ---------------- float4 zero (n % 1024 == 0) ----------------
__global__ __launch_bounds__(256) void zero4_k(float* __restrict__ p) {
    int i = (blockIdx.x * 256 + threadIdx.x) * 4;
    *(float4*)(p + i) = make_float4(0.f, 0.f, 0.f, 0.f);
}

// ---------------- fp16 MFMA GEMM: C = act(A(MxK) * B(NxK)^T + bias) [+C] ------
template<int ACT>   // 0 none, 1 relu
__global__ __launch_bounds__(256) void hgemm_nt(
    const _Float16* __restrict__ A, int lda,
    const _Float16* __restrict__ B, int ldb,
    float* __restrict__ C, int ldc,
    const float* __restrict__ bias, int K, int accum)
{
    __shared__ _Float16 As[128][40];   // pad 32->40: 2-way bank alias only (free)
    __shared__ _Float16 Bs[128][40];
    int tid = threadIdx.x;
    int m0 = blockIdx.y * 128, n0 = blockIdx.x * 128;
    int lane = tid & 63, wave = tid >> 6;
    int wm = (wave >> 1) * 64, wn = (wave & 1) * 64;
    int quad = lane >> 4, r16 = lane & 15;
    v4f acc[4][4] = {};

    int srow = tid >> 1;            // 0..127
    int scol = (tid & 1) * 16;      // 0 or 16
    const _Float16* Ag = A + (size_t)(m0 + srow) * lda + scol;
    const _Float16* Bg = B + (size_t)(n0 + srow) * ldb + scol;

    for (int k0 = 0; k0 < K; k0 += 32) {
        uint4 a0 = *(const uint4*)(Ag + k0);
        uint4 a1 = *(const uint4*)(Ag + k0 + 8);
        uint4 b0 = *(const uint4*)(Bg + k0);
        uint4 b1 = *(const uint4*)(Bg + k0 + 8);
        __syncthreads();
        *(uint4*)&As[srow][scol] = a0;
        *(uint4*)&As[srow][scol + 8] = a1;
        *(uint4*)&Bs[srow][scol] = b0;
        *(uint4*)&Bs[srow][scol + 8] = b1;
        __syncthreads();
        v8h af[4], bf[4];
#pragma unroll
        for (int i = 0; i < 4; ++i)
            af[i] = *(const v8h*)&As[wm + i * 16 + r16][quad * 8];
#pragma unroll
        for (int j = 0; j < 4; ++j)
            bf[j] = *(const v8h*)&Bs[wn + j * 16 + r16][quad * 8];
#pragma unroll
        for (int i = 0; i < 4; ++i)
#pragma unroll
            for (int j = 0; j < 4; ++j)
                acc[i][j] = __builtin_amdgcn_mfma_f32_16x16x32_f16(
                    af[i], bf[j], acc[i][j], 0, 0, 0);
    }

    // C/D layout: col = lane&15, row = (lane>>4)*4 + reg
#pragma unroll
    for (int i = 0; i < 4; ++i) {
#pragma unroll
        for (int j = 0; j < 4; ++j) {
            int col = n0 + wn + j * 16 + r16;
            int rbase = m0 + wm + i * 16 + quad * 4;
            float bv = bias ? bias[col] : 0.f;
#pragma unroll
            for (int r = 0; r < 4; ++r) {
                float v = acc[i][j][r] + bv;
                if (ACT == 1) v = fmaxf(v, 0.f);
                float* p = C + (size_t)(rbase + r) * ldc + col;
                if (accum) v += *p;
                *p = v;
            }
        }
    }
}

// ---------------- generic fp32 GEMM (small shapes): C = act(A*B^T + bias) ----
// ACT: 0 none, 2 softplus, 3 tanh
// Split-K: block processes K range [blockIdx.z*kchunk, min(K, +kchunk)).
// accum: 0 store, 1 add-to-C, 2 atomicAdd (split-K partials; ACT must be 0).
#define BM 64
#define BN 64
#define BKK 32
template<int ACT>
__global__ __launch_bounds__(256) void gemm_nt(
    const float* __restrict__ A, int lda,
    const float* __restrict__ B, int ldb,
    float* __restrict__ C, int ldc,
    const float* __restrict__ bias,
    int M, int N, int K, int kchunk, int accum)
{
    __shared__ float As[BKK][BM + 4];
    __shared__ float Bs[BKK][BN + 4];
    int tid = threadIdx.x;
    int m0 = blockIdx.y * BM;
    int n0 = blockIdx.x * BN;
    int tx = tid & 15, ty = tid >> 4;
    float acc[4][4] = {};
    int arow = tid >> 3;       // 0..31
    int ak = (tid & 7) * 4;    // 0..28
    int kb = blockIdx.z * kchunk;
    int ke = min(K, kb + kchunk);

    for (int k0 = kb; k0 < ke; k0 += BKK) {
#pragma unroll
        for (int r = 0; r < 2; ++r) {
            int row = arow + r * 32;
            float4 va = *(const float4*)(A + (size_t)(m0 + row) * lda + k0 + ak);
            As[ak + 0][row] = va.x; As[ak + 1][row] = va.y;
            As[ak + 2][row] = va.z; As[ak + 3][row] = va.w;
            float4 vb = *(const float4*)(B + (size_t)(n0 + row) * ldb + k0 + ak);
            Bs[ak + 0][row] = vb.x; Bs[ak + 1][row] = vb.y;
            Bs[ak + 2][row] = vb.z; Bs[ak + 3][row] = vb.w;
        }
        __syncthreads();
#pragma unroll
        for (int kk = 0; kk < BKK; ++kk) {
            float4 a4 = *(const float4*)&As[kk][ty * 4];
            float4 b4 = *(const float4*)&Bs[kk][tx * 4];
            float a[4] = {a4.x, a4.y, a4.z, a4.w};
            float b[4] = {b4.x, b4.y, b4.z, b4.w};
#pragma unroll
            for (int i = 0; i < 4; ++i)
#pragma unroll
                for (int j = 0; j < 4; ++j)
                    acc[i][j] = fmaf(a[i], b[j], acc[i][j]);
        }
        __syncthreads();
    }

#pragma unroll
    for (int i = 0; i < 4; ++i) {
        int row = m0 + ty * 4 + i;
        int col = n0 + tx * 4;
        float* cp = C + (size_t)row * ldc + col;
        if (accum == 2) {
#pragma unroll
            for (int j = 0; j < 4; ++j) atomicAdd(cp + j, acc[i][j]);
            continue;
        }
        float v[4];
#pragma unroll
        for (int j = 0; j < 4; ++j) {
            float x = acc[i][j] + (bias ? bias[col + j] : 0.f);
            if (ACT == 2) x = (x > 20.f) ? x : log1pf(expf(x));
            else if (ACT == 3) x = tanhf(x);
            v[j] = x;
        }
        if (accum == 1) {
#pragma unroll
            for (int j = 0; j < 4; ++j) v[j] += cp[j];
        }
#pragma unroll
        for (int j = 0; j < 4; ++j) cp[j] = v[j];
    }
}

// ---------------- layernorm (D=512), optional fp16 side-output ----------------
__global__ __launch_bounds__(256) void layernorm_k(
    const float* __restrict__ x, const float* __restrict__ w,
    const float* __restrict__ b, float* __restrict__ o,
    _Float16* __restrict__ oh)
{
    int row = blockIdx.x;
    int tid = threadIdx.x;
    const float* xr = x + (size_t)row * DM;
    float v0 = xr[tid], v1 = xr[tid + 256];
    float s = v0 + v1, ss = v0 * v0 + v1 * v1;
    for (int off = 32; off; off >>= 1) {
        s += __shfl_down(s, off, 64);
        ss += __shfl_down(ss, off, 64);
    }
    __shared__ float sm[4], sm2[4];
    int wave = tid >> 6, lane = tid & 63;
    if (lane == 0) { sm[wave] = s; sm2[wave] = ss; }
    __syncthreads();
    float tot = sm[0] + sm[1] + sm[2] + sm[3];
    float tot2 = sm2[0] + sm2[1] + sm2[2] + sm2[3];
    float mu = tot * (1.f / DM);
    float var = tot2 * (1.f / DM) - mu * mu;
    float rs = rsqrtf(var + 1e-5f);
    float y0 = (v0 - mu) * rs * w[tid] + b[tid];
    float y1 = (v1 - mu) * rs * w[tid + 256] + b[tid + 256];
    o[(size_t)row * DM + tid] = y0;
    o[(size_t)row * DM + tid + 256] = y1;
    if (oh) {
        oh[(size_t)row * DM + tid] = (_Float16)y0;
        oh[(size_t)row * DM + tid + 256] = (_Float16)y1;
    }
}

// ---------------- permuted causal conv (K=4) + SiLU ----------------
__global__ __launch_bounds__(256) void conv_silu_k(
    const float* __restrict__ xz, const int* __restrict__ perm,
    const float* __restrict__ cw, const float* __restrict__ cb,
    float* __restrict__ xc)
{
    int g = blockIdx.x * 256 + threadIdx.x;   // g < L*DI
    int c = g & (DI - 1), p = g >> 10;
    float acc = cb[c];
#pragma unroll
    for (int k = 0; k < 4; ++k) {
        int q = p + k - 3;
        if (q >= 0)
            acc = fmaf(xz[(size_t)perm[q] * (2 * DI) + c], cw[c * 4 + k], acc);
    }
    float sig = 1.f / (1.f + __expf(-acc));
    xc[g] = acc * sig;
}

// ---------------- chunked parallel selective scan ----------------
// One thread per (channel, chunk); 16 states in registers.
__global__ __launch_bounds__(256) void scan_pass1(
    const float* __restrict__ dt, const float* __restrict__ u,
    const float* __restrict__ dbl, const float* __restrict__ A_log,
    float* __restrict__ Aprod, float* __restrict__ carry)
{
    int c = blockIdx.x * 256 + threadIdx.x;
    int j = blockIdx.y;
    float Ac[16];
#pragma unroll
    for (int s = 0; s < 16; ++s) Ac[s] = -__expf(A_log[c * DS + s]);
    float ap[16], h[16];
#pragma unroll
    for (int s = 0; s < 16; ++s) { ap[s] = 1.f; h[s] = 0.f; }
    int t0 = j * CHK;
    for (int tt = 0; tt < CHK; ++tt) {
        int t = t0 + tt;
        float dtv = dt[(size_t)t * DI + c];
        float uv  = u[(size_t)t * DI + c];
        v4f Bv[4];
#pragma unroll
        for (int q = 0; q < 4; ++q)
            Bv[q] = *(const v4f*)(dbl + (size_t)t * 64 + DTR + q * 4);
        float du = dtv * uv;
#pragma unroll
        for (int s = 0; s < 16; ++s) {
            float dA = __expf(dtv * Ac[s]);
            h[s] = fmaf(dA, h[s], du * Bv[s >> 2][s & 3]);
            ap[s] *= dA;
        }
    }
    size_t base = ((size_t)j * DI + c) * DS;
#pragma unroll
    for (int q = 0; q < 4; ++q) {
        *(v4f*)(Aprod + base + q * 4) = *(v4f*)&ap[q * 4];
        *(v4f*)(carry + base + q * 4) = *(v4f*)&h[q * 4];
    }
}

// Pass 2: exclusive prefix across chunks per (c,s).
__global__ __launch_bounds__(256) void scan_pass2(
    const float* __restrict__ Aprod, const float* __restrict__ carry,
    float* __restrict__ Hin)
{
    int idx = blockIdx.x * 256 + threadIdx.x;  // (c,s) flat, 16384 total
    float H = 0.f;
    Hin[idx] = 0.f;
    for (int j = 1; j < NCH; ++j) {
        H = fmaf(Aprod[(size_t)(j - 1) * (DI * DS) + idx], H,
                 carry[(size_t)(j - 1) * (DI * DS) + idx]);
        Hin[(size_t)j * (DI * DS) + idx] = H;
    }
}

// Pass 3: seeded local scan; gated output scattered, written fp16 for out_proj.
__global__ __launch_bounds__(256) void scan_pass3(
    const float* __restrict__ dt, const float* __restrict__ u,
    const float* __restrict__ dbl, const float* __restrict__ xz,
    const float* __restrict__ A_log, const float* __restrict__ Dsk,
    const int* __restrict__ perm, const float* __restrict__ Hin,
    _Float16* __restrict__ yo)
{
    int c = blockIdx.x * 256 + threadIdx.x;
    int j = blockIdx.y;
    float Ac[16];
#pragma unroll
    for (int s = 0; s < 16; ++s) Ac[s] = -__expf(A_log[c * DS + s]);
    float Dp = Dsk[c];
    float h[16];
    size_t hbase = ((size_t)j * DI + c) * DS;
#pragma unroll
    for (int q = 0; q < 4; ++q)
        *(v4f*)&h[q * 4] = *(const v4f*)(Hin + hbase + q * 4);
    int t0 = j * CHK;
    for (int tt = 0; tt < CHK; ++tt) {
        int t = t0 + tt;
        float dtv = dt[(size_t)t * DI + c];
        float uv  = u[(size_t)t * DI + c];
        v4f Bv[4], Cv[4];
#pragma unroll
        for (int q = 0; q < 4; ++q) {
            Bv[q] = *(const v4f*)(dbl + (size_t)t * 64 + DTR + q * 4);
            Cv[q] = *(const v4f*)(dbl + (size_t)t * 64 + DTR + DS + q * 4);
        }
        float du = dtv * uv;
        float y = 0.f;
#pragma unroll
        for (int s = 0; s < 16; ++s) {
            float dA = __expf(dtv * Ac[s]);
            h[s] = fmaf(dA, h[s], du * Bv[s >> 2][s & 3]);
            y = fmaf(h[s], Cv[s >> 2][s & 3], y);
        }
        int tp = perm[t];
        float z = xz[(size_t)tp * (2 * DI) + DI + c];
        float sig = 1.f / (1.f + __expf(-z));
        yo[(size_t)tp * DI + c] = (_Float16)((y + uv * Dp) * (z * sig));
    }
}

// ---------------- attention score: avec[t] = t1[t,:] . w2 + b2 ----------------
__global__ __launch_bounds__(256) void attnscore_k(
    const float* __restrict__ t1, const float* __restrict__ w2,
    const float* __restrict__ b2, float* __restrict__ avec)
{
    int t = blockIdx.x * 256 + threadIdx.x;
    const float* r = t1 + (size_t)t * 128;
    float acc = 0.f;
#pragma unroll 8
    for (int j = 0; j < 128; ++j) acc = fmaf(r[j], w2[j], acc);
    avec[t] = acc + b2[0];
}

// ---------------- softmax over 4096 (single block) ----------------
__global__ __launch_bounds__(1024) void softmax_k(
    const float* __restrict__ a, float* __restrict__ out)
{
    int tid = threadIdx.x;
    float v[4];
    float mx = -1e30f;
#pragma unroll
    for (int i = 0; i < 4; ++i) { v[i] = a[tid + i * 1024]; mx = fmaxf(mx, v[i]); }
    __shared__ float sm[16];
    for (int off = 32; off; off >>= 1) mx = fmaxf(mx, __shfl_xor(mx, off, 64));
    int wave = tid >> 6, lane = tid & 63;
    if (lane == 0) sm[wave] = mx;
    __syncthreads();
    if (tid < 16) {
        float m = sm[tid];
        for (int off = 8; off; off >>= 1) m = fmaxf(m, __shfl_xor(m, off, 64));
        sm[tid] = m;
    }
    __syncthreads();
    mx = sm[0];
    float s = 0.f;
#pragma unroll
    for (int i = 0; i < 4; ++i) { v[i] = __expf(v[i] - mx); s += v[i]; }
    for (int off = 32; off; off >>= 1) s += __shfl_xor(s, off, 64);
    __syncthreads();
    if (lane == 0) sm[wave] = s;
    __syncthreads();
    if (tid < 16) {
        float t2 = sm[tid];
        for (int off = 8; off; off >>= 1) t2 += __shfl_xor(t2, off, 64);
        sm[tid] = t2;
    }
    __syncthreads();
    float inv = 1.f / sm[0];
#pragma unroll
    for (int i = 0; i < 4; ++i) out[tid + i * 1024] = v[i] * inv;
}

__global__ void zero_k(float* p, int n) {
    int i = blockIdx.x * 256 + threadIdx.x;
    if (i < n) p[i] = 0.f;
}

__global__ __launch_bounds__(512) void pool_k(
    const float* __restrict__ aatt, const float* __restrict__ h,
    float* __restrict__ pooled)
{
    int m = threadIdx.x;
    int t0 = blockIdx.x * 128;
    float acc = 0.f;
    for (int r = 0; r < 128; ++r) {
        int t = t0 + r;
        acc = fmaf(aatt[t], h[(size_t)t * DM + m], acc);
    }
    atomicAdd(&pooled[m], acc);
}

__global__ __launch_bounds__(64) void out2048_k(
    const float* __restrict__ pooled, const float* __restrict__ w,
    const float* __restrict__ b, float* __restrict__ out)
{
    int n = blockIdx.x;
    int lane = threadIdx.x;
    const float* wr = w + (size_t)n * DM;
    float acc = 0.f;
#pragma unroll
    for (int k = 0; k < 8; ++k)
        acc = fmaf(wr[lane + k * 64], pooled[lane + k * 64], acc);
    for (int off = 32; off; off >>= 1) acc += __shfl_xor(acc, off, 64);
    if (lane == 0) out[n] = acc + b[n];
}

extern "C" void kernel_launch(void* const* d_in, const int* in_sizes, int n_in,
                              void* d_out, int out_size, void* d_ws, size_t ws_size,
                              hipStream_t stream) {
    const float* x     = (const float*)d_in[0];
    const int*   rate  = (const int*)d_in[1];
    const float* fc1_w = (const float*)d_in[2];
    const float* fc1_b = (const float*)d_in[3];
    const float* ln_w  = (const float*)d_in[4];
    const float* ln_b  = (const float*)d_in[5];
    const float* ipw   = (const float*)d_in[6];
    const float* cw    = (const float*)d_in[7];
    const float* cb    = (const float*)d_in[8];
    const float* xpw   = (const float*)d_in[9];
    const float* dtw   = (const float*)d_in[10];
    const float* dtpb  = (const float*)d_in[11];
    const float* A_log = (const float*)d_in[12];
    const float* Dsk   = (const float*)d_in[13];
    const float* opw   = (const float*)d_in[14];
    const float* nw    = (const float*)d_in[15];
    const float* nb    = (const float*)d_in[16];
    const float* aw1   = (const float*)d_in[17];
    const float* ab1   = (const float*)d_in[18];
    const float* aw2   = (const float*)d_in[19];
    const float* ab2   = (const float*)d_in[20];
    const float* ow    = (const float*)d_in[21];
    const float* ob    = (const float*)d_in[22];
    float* out = (float*)d_out;

    int* perm = (int*)d_ws;
    float* f = (float*)d_ws + 4096;
    float* h    = f; f += (size_t)L * DM;
    float* hln  = f; f += (size_t)L * DM;
    float* xz   = f; f += (size_t)L * 2 * DI;
    float* xc   = f; f += (size_t)L * DI;
    float* dbl  = f; f += (size_t)L * 64;
    float* dtv  = f; f += (size_t)L * DI;
    float* t1   = f; f += (size_t)L * 128;
    float* avec = f; f += L;
    float* pooled = f; f += DM;
    float* Aprod = f; f += (size_t)NCH * DI * DS;
    float* carry = f; f += (size_t)NCH * DI * DS;
    float* Hin   = f; f += (size_t)NCH * DI * DS;
    _Float16* fh = (_Float16*)f;
    _Float16* xh     = fh; fh += (size_t)L * DIN;
    _Float16* hln_h  = fh; fh += (size_t)L * DM;
    _Float16* yo_h   = fh; fh += (size_t)L * DI;
    _Float16* fc1w_h = fh; fh += (size_t)DM * DIN;
    _Float16* ipw_h  = fh; fh += (size_t)2 * 2 * DI * DM;
    _Float16* opw_h  = fh; fh += (size_t)2 * DM * DI;

    perm_k<<<16, 256, 0, stream>>>(perm, rate);

    // weight / input conversions to fp16 (cheap, memory-bound)
    f2h_k<<<L * DIN / 1024, 256, 0, stream>>>(x, xh);
    f2h_k<<<DM * DIN / 1024, 256, 0, stream>>>(fc1_w, fc1w_h);
    f2h_k<<<2 * 2 * DI * DM / 1024, 256, 0, stream>>>(ipw, ipw_h);
    f2h_k<<<2 * DM * DI / 1024, 256, 0, stream>>>(opw, opw_h);

    // h = relu(x @ fc1_w^T + fc1_b)   [fp16 MFMA]
    hgemm_nt<1><<<dim3(DM / 128, L / 128), 256, 0, stream>>>(
        xh, DIN, fc1w_h, DIN, h, DM, fc1_b, DIN, 0);

    for (int l = 0; l < 2; ++l) {
        layernorm_k<<<L, 256, 0, stream>>>(h, ln_w + l * DM, ln_b + l * DM, hln, hln_h);
        // xz = hln @ in_proj^T   [fp16 MFMA]
        hgemm_nt<0><<<dim3(2 * DI / 128, L / 128), 256, 0, stream>>>(
            hln_h, DM, ipw_h + (size_t)l * 2 * DI * DM, DM, xz, 2 * DI,
            nullptr, DM, 0);
        // xc = silu(causal_conv(x_perm))
        conv_silu_k<<<L * DI / 256, 256, 0, stream>>>(
            xz, perm, cw + (size_t)l * DI * 4, cb + (size_t)l * DI, xc);
        // dbl = xc @ x_proj^T  (N=64; split-K x4 for occupancy, atomic partials)
        zero4_k<<<L * 64 / 1024, 256, 0, stream>>>(dbl);
        gemm_nt<0><<<dim3(1, L / 64, 4), 256, 0, stream>>>(
            xc, DI, xpw + (size_t)l * 64 * DI, DI, dbl, 64, nullptr,
            L, 64, DI, DI / 4, 2);
        // dt = softplus(dbl[:, :32] @ dt_proj^T + dtb)  (K=32, fp32 SIMT)
        gemm_nt<2><<<dim3(DI / 64, L / 64), 256, 0, stream>>>(
            dbl, 64, dtw + (size_t)l * DI * DTR, DTR, dtv, DI,
            dtpb + (size_t)l * DI, L, DI, DTR, DTR, 0);
        // chunked parallel selective scan (channel-per-thread, states in regs)
        scan_pass1<<<dim3(DI / 256, NCH), 256, 0, stream>>>(
            dtv, xc, dbl, A_log + (size_t)l * DI * DS, Aprod, carry);
        scan_pass2<<<DI * DS / 256, 256, 0, stream>>>(Aprod, carry, Hin);
        scan_pass3<<<dim3(DI / 256, NCH), 256, 0, stream>>>(
            dtv, xc, dbl, xz, A_log + (size_t)l * DI * DS, Dsk + (size_t)l * DI,
            perm, Hin, yo_h);
        // h += yo @ out_proj^T   [fp16 MFMA, accumulate]
        hgemm_nt<0><<<dim3(DM / 128, L / 128), 256, 0, stream>>>(
            yo_h, DI, opw_h + (size_t)l * DM * DI, DI, h, DM, nullptr, DI, 1);
    }

    layernorm_k<<<L, 256, 0, stream>>>(h, nw, nb, hln, nullptr);
    // t1 = tanh(hln @ aw1^T + ab1)  (fp32 SIMT)
    gemm_nt<3><<<dim3(128 / 64, L / 64), 256, 0, stream>>>(
        hln, DM, aw1, DM, t1, 128, ab1, L, 128, DM, DM, 0);
    attnscore_k<<<L / 256, 256, 0, stream>>>(t1, aw2, ab2, avec);
    softmax_k<<<1, 1024, 0, stream>>>(avec, out + 2048);
    zero_k<<<2, 256, 0, stream>>>(pooled, DM);
    pool_k<<<32, 512, 0, stream>>>(out + 2048, hln, pooled);
    out2048_k<<<2048, 64, 0, stream>>>(pooled, ow, ob, out);
}

// Round 6
// 608.797 us; speedup vs baseline: 12.1484x; 1.0843x over previous
//
#include <hip/hip_runtime.h>
#include <hip/hip_fp16.h>
#include <math.h>

#define L 4096
#define DIN 1024
#define DM 512
#define DI 1024
#define DS 16
#define DTR 32
#define NCH 128
#define CHK 32   // NCH*CHK == L

typedef _Float16 v8h __attribute__((ext_vector_type(8)));
typedef float v4f __attribute__((ext_vector_type(4)));

// ---------------- perm table ----------------
__global__ void perm_k(int* __restrict__ perm, const int* __restrict__ ratep) {
    int p = blockIdx.x * blockDim.x + threadIdx.x;
    if (p >= L) return;
    int rate = ratep[0];
    int cum = 0;
    for (int g = 0; g < rate; ++g) {
        int sz = (L - g + rate - 1) / rate;
        if (p < cum + sz) { perm[p] = g + rate * (p - cum); return; }
        cum += sz;
    }
}

// ---------------- fp32 -> fp16 convert (n % 1024 == 0) ----------------
__global__ __launch_bounds__(256) void f2h_k(
    const float* __restrict__ in, _Float16* __restrict__ out)
{
    int i = (blockIdx.x * 256 + threadIdx.x) * 4;
    float4 v = *(const float4*)(in + i);
    _Float16 h4[4] = {(_Float16)v.x, (_Float16)v.y, (_Float16)v.z, (_Float16)v.w};
    *(uint2*)(out + i) = *(uint2*)h4;
}

// ---------------- float4 zero (n % 1024 == 0) ----------------
__global__ __launch_bounds__(256) void zero4_k(float* __restrict__ p) {
    int i = (blockIdx.x * 256 + threadIdx.x) * 4;
    *(float4*)(p + i) = make_float4(0.f, 0.f, 0.f, 0.f);
}

// ---------------- fp16 MFMA GEMM: C = act(A(MxK) * B(NxK)^T + bias) [+C] ------
// Block tile 128 x BNT. BNT=128: 4 waves of 64x64. BNT=64: 4 waves of 32x64
// (grid doubles in N -> full CU coverage for N=512 shapes).
// Register-prefetch of tile k+1 overlaps global latency with ds_read+MFMA.
template<int ACT, int BNT>   // ACT: 0 none, 1 relu
__global__ __launch_bounds__(256) void hgemm_nt(
    const _Float16* __restrict__ A, int lda,
    const _Float16* __restrict__ B, int ldb,
    float* __restrict__ C, int ldc,
    const float* __restrict__ bias, int K, int accum)
{
    constexpr int MI = (BNT == 128) ? 4 : 2;
    __shared__ _Float16 As[128][40];   // pad 32->40: 2-way bank alias only (free)
    __shared__ _Float16 Bs[BNT][40];
    int tid = threadIdx.x;
    int m0 = blockIdx.y * 128, n0 = blockIdx.x * BNT;
    int lane = tid & 63, wave = tid >> 6;
    int wm, wn;
    if constexpr (BNT == 128) { wm = (wave >> 1) * 64; wn = (wave & 1) * 64; }
    else                      { wm = wave * 32;        wn = 0; }
    int quad = lane >> 4, r16 = lane & 15;
    v4f acc[MI][4] = {};

    int srow = tid >> 1;            // 0..127
    int scol = (tid & 1) * 16;      // 0 or 16
    const _Float16* Ag = A + (size_t)(m0 + srow) * lda + scol;
    // B staging: BNT=128 mirrors A; BNT=64 uses 64 rows x 32 cols, 8 halfs/thread
    int srowB = (BNT == 128) ? srow : (tid >> 2);
    int scolB = (BNT == 128) ? scol : (tid & 3) * 8;
    const _Float16* Bg = B + (size_t)(n0 + srowB) * ldb + scolB;

    uint4 a0, a1, b0, b1;
    a0 = *(const uint4*)(Ag);
    a1 = *(const uint4*)(Ag + 8);
    b0 = *(const uint4*)(Bg);
    if constexpr (BNT == 128) b1 = *(const uint4*)(Bg + 8);

    int KS = K / 32;
    for (int ks = 0; ks < KS; ++ks) {
        __syncthreads();
        *(uint4*)&As[srow][scol] = a0;
        *(uint4*)&As[srow][scol + 8] = a1;
        *(uint4*)&Bs[srowB][scolB] = b0;
        if constexpr (BNT == 128) *(uint4*)&Bs[srowB][scolB + 8] = b1;
        __syncthreads();
        if (ks + 1 < KS) {
            int k0 = (ks + 1) * 32;
            a0 = *(const uint4*)(Ag + k0);
            a1 = *(const uint4*)(Ag + k0 + 8);
            b0 = *(const uint4*)(Bg + k0);
            if constexpr (BNT == 128) b1 = *(const uint4*)(Bg + k0 + 8);
        }
        v8h af[MI], bf[4];
#pragma unroll
        for (int i = 0; i < MI; ++i)
            af[i] = *(const v8h*)&As[wm + i * 16 + r16][quad * 8];
#pragma unroll
        for (int j = 0; j < 4; ++j)
            bf[j] = *(const v8h*)&Bs[wn + j * 16 + r16][quad * 8];
#pragma unroll
        for (int i = 0; i < MI; ++i)
#pragma unroll
            for (int j = 0; j < 4; ++j)
                acc[i][j] = __builtin_amdgcn_mfma_f32_16x16x32_f16(
                    af[i], bf[j], acc[i][j], 0, 0, 0);
    }

    // C/D layout: col = lane&15, row = (lane>>4)*4 + reg
#pragma unroll
    for (int i = 0; i < MI; ++i) {
#pragma unroll
        for (int j = 0; j < 4; ++j) {
            int col = n0 + wn + j * 16 + r16;
            int rbase = m0 + wm + i * 16 + quad * 4;
            float bv = bias ? bias[col] : 0.f;
#pragma unroll
            for (int r = 0; r < 4; ++r) {
                float v = acc[i][j][r] + bv;
                if (ACT == 1) v = fmaxf(v, 0.f);
                float* p = C + (size_t)(rbase + r) * ldc + col;
                if (accum) v += *p;
                *p = v;
            }
        }
    }
}

// ---------------- generic fp32 GEMM (small shapes): C = act(A*B^T + bias) ----
// ACT: 0 none, 2 softplus, 3 tanh
// Split-K: block processes K range [blockIdx.z*kchunk, min(K, +kchunk)).
// accum: 0 store, 1 add-to-C, 2 atomicAdd (split-K partials; ACT must be 0).
#define BM 64
#define BN 64
#define BKK 32
template<int ACT>
__global__ __launch_bounds__(256) void gemm_nt(
    const float* __restrict__ A, int lda,
    const float* __restrict__ B, int ldb,
    float* __restrict__ C, int ldc,
    const float* __restrict__ bias,
    int M, int N, int K, int kchunk, int accum)
{
    __shared__ float As[BKK][BM + 4];
    __shared__ float Bs[BKK][BN + 4];
    int tid = threadIdx.x;
    int m0 = blockIdx.y * BM;
    int n0 = blockIdx.x * BN;
    int tx = tid & 15, ty = tid >> 4;
    float acc[4][4] = {};
    int arow = tid >> 3;       // 0..31
    int ak = (tid & 7) * 4;    // 0..28
    int kb = blockIdx.z * kchunk;
    int ke = min(K, kb + kchunk);

    for (int k0 = kb; k0 < ke; k0 += BKK) {
#pragma unroll
        for (int r = 0; r < 2; ++r) {
            int row = arow + r * 32;
            float4 va = *(const float4*)(A + (size_t)(m0 + row) * lda + k0 + ak);
            As[ak + 0][row] = va.x; As[ak + 1][row] = va.y;
            As[ak + 2][row] = va.z; As[ak + 3][row] = va.w;
            float4 vb = *(const float4*)(B + (size_t)(n0 + row) * ldb + k0 + ak);
            Bs[ak + 0][row] = vb.x; Bs[ak + 1][row] = vb.y;
            Bs[ak + 2][row] = vb.z; Bs[ak + 3][row] = vb.w;
        }
        __syncthreads();
#pragma unroll
        for (int kk = 0; kk < BKK; ++kk) {
            float4 a4 = *(const float4*)&As[kk][ty * 4];
            float4 b4 = *(const float4*)&Bs[kk][tx * 4];
            float a[4] = {a4.x, a4.y, a4.z, a4.w};
            float b[4] = {b4.x, b4.y, b4.z, b4.w};
#pragma unroll
            for (int i = 0; i < 4; ++i)
#pragma unroll
                for (int j = 0; j < 4; ++j)
                    acc[i][j] = fmaf(a[i], b[j], acc[i][j]);
        }
        __syncthreads();
    }

#pragma unroll
    for (int i = 0; i < 4; ++i) {
        int row = m0 + ty * 4 + i;
        int col = n0 + tx * 4;
        float* cp = C + (size_t)row * ldc + col;
        if (accum == 2) {
#pragma unroll
            for (int j = 0; j < 4; ++j) atomicAdd(cp + j, acc[i][j]);
            continue;
        }
        float v[4];
#pragma unroll
        for (int j = 0; j < 4; ++j) {
            float x = acc[i][j] + (bias ? bias[col + j] : 0.f);
            if (ACT == 2) x = (x > 20.f) ? x : log1pf(expf(x));
            else if (ACT == 3) x = tanhf(x);
            v[j] = x;
        }
        if (accum == 1) {
#pragma unroll
            for (int j = 0; j < 4; ++j) v[j] += cp[j];
        }
#pragma unroll
        for (int j = 0; j < 4; ++j) cp[j] = v[j];
    }
}

// ---------------- layernorm (D=512), optional fp16 side-output ----------------
__global__ __launch_bounds__(256) void layernorm_k(
    const float* __restrict__ x, const float* __restrict__ w,
    const float* __restrict__ b, float* __restrict__ o,
    _Float16* __restrict__ oh)
{
    int row = blockIdx.x;
    int tid = threadIdx.x;
    const float* xr = x + (size_t)row * DM;
    float v0 = xr[tid], v1 = xr[tid + 256];
    float s = v0 + v1, ss = v0 * v0 + v1 * v1;
    for (int off = 32; off; off >>= 1) {
        s += __shfl_down(s, off, 64);
        ss += __shfl_down(ss, off, 64);
    }
    __shared__ float sm[4], sm2[4];
    int wave = tid >> 6, lane = tid & 63;
    if (lane == 0) { sm[wave] = s; sm2[wave] = ss; }
    __syncthreads();
    float tot = sm[0] + sm[1] + sm[2] + sm[3];
    float tot2 = sm2[0] + sm2[1] + sm2[2] + sm2[3];
    float mu = tot * (1.f / DM);
    float var = tot2 * (1.f / DM) - mu * mu;
    float rs = rsqrtf(var + 1e-5f);
    float y0 = (v0 - mu) * rs * w[tid] + b[tid];
    float y1 = (v1 - mu) * rs * w[tid + 256] + b[tid + 256];
    o[(size_t)row * DM + tid] = y0;
    o[(size_t)row * DM + tid + 256] = y1;
    if (oh) {
        oh[(size_t)row * DM + tid] = (_Float16)y0;
        oh[(size_t)row * DM + tid + 256] = (_Float16)y1;
    }
}

// ---------------- permuted causal conv (K=4) + SiLU ----------------
__global__ __launch_bounds__(256) void conv_silu_k(
    const float* __restrict__ xz, const int* __restrict__ perm,
    const float* __restrict__ cw, const float* __restrict__ cb,
    float* __restrict__ xc)
{
    int g = blockIdx.x * 256 + threadIdx.x;   // g < L*DI
    int c = g & (DI - 1), p = g >> 10;
    float acc = cb[c];
#pragma unroll
    for (int k = 0; k < 4; ++k) {
        int q = p + k - 3;
        if (q >= 0)
            acc = fmaf(xz[(size_t)perm[q] * (2 * DI) + c], cw[c * 4 + k], acc);
    }
    float sig = 1.f / (1.f + __expf(-acc));
    xc[g] = acc * sig;
}

// ---------------- chunked parallel selective scan ----------------
// One thread per (channel, chunk); 16 states in registers.
__global__ __launch_bounds__(256) void scan_pass1(
    const float* __restrict__ dt, const float* __restrict__ u,
    const float* __restrict__ dbl, const float* __restrict__ A_log,
    float* __restrict__ Aprod, float* __restrict__ carry)
{
    int c = blockIdx.x * 256 + threadIdx.x;
    int j = blockIdx.y;
    float Ac[16];
#pragma unroll
    for (int s = 0; s < 16; ++s) Ac[s] = -__expf(A_log[c * DS + s]);
    float ap[16], h[16];
#pragma unroll
    for (int s = 0; s < 16; ++s) { ap[s] = 1.f; h[s] = 0.f; }
    int t0 = j * CHK;
    for (int tt = 0; tt < CHK; ++tt) {
        int t = t0 + tt;
        float dtv = dt[(size_t)t * DI + c];
        float uv  = u[(size_t)t * DI + c];
        v4f Bv[4];
#pragma unroll
        for (int q = 0; q < 4; ++q)
            Bv[q] = *(const v4f*)(dbl + (size_t)t * 64 + DTR + q * 4);
        float du = dtv * uv;
#pragma unroll
        for (int s = 0; s < 16; ++s) {
            float dA = __expf(dtv * Ac[s]);
            h[s] = fmaf(dA, h[s], du * Bv[s >> 2][s & 3]);
            ap[s] *= dA;
        }
    }
    size_t base = ((size_t)j * DI + c) * DS;
#pragma unroll
    for (int q = 0; q < 4; ++q) {
        *(v4f*)(Aprod + base + q * 4) = *(v4f*)&ap[q * 4];
        *(v4f*)(carry + base + q * 4) = *(v4f*)&h[q * 4];
    }
}

// Pass 2: exclusive prefix across chunks per (c,s).
__global__ __launch_bounds__(256) void scan_pass2(
    const float* __restrict__ Aprod, const float* __restrict__ carry,
    float* __restrict__ Hin)
{
    int idx = blockIdx.x * 256 + threadIdx.x;  // (c,s) flat, 16384 total
    float H = 0.f;
    Hin[idx] = 0.f;
    for (int j = 1; j < NCH; ++j) {
        H = fmaf(Aprod[(size_t)(j - 1) * (DI * DS) + idx], H,
                 carry[(size_t)(j - 1) * (DI * DS) + idx]);
        Hin[(size_t)j * (DI * DS) + idx] = H;
    }
}

// Pass 3: seeded local scan; gated output scattered, written fp16 for out_proj.
__global__ __launch_bounds__(256) void scan_pass3(
    const float* __restrict__ dt, const float* __restrict__ u,
    const float* __restrict__ dbl, const float* __restrict__ xz,
    const float* __restrict__ A_log, const float* __restrict__ Dsk,
    const int* __restrict__ perm, const float* __restrict__ Hin,
    _Float16* __restrict__ yo)
{
    int c = blockIdx.x * 256 + threadIdx.x;
    int j = blockIdx.y;
    float Ac[16];
#pragma unroll
    for (int s = 0; s < 16; ++s) Ac[s] = -__expf(A_log[c * DS + s]);
    float Dp = Dsk[c];
    float h[16];
    size_t hbase = ((size_t)j * DI + c) * DS;
#pragma unroll
    for (int q = 0; q < 4; ++q)
        *(v4f*)&h[q * 4] = *(const v4f*)(Hin + hbase + q * 4);
    int t0 = j * CHK;
    for (int tt = 0; tt < CHK; ++tt) {
        int t = t0 + tt;
        float dtv = dt[(size_t)t * DI + c];
        float uv  = u[(size_t)t * DI + c];
        v4f Bv[4], Cv[4];
#pragma unroll
        for (int q = 0; q < 4; ++q) {
            Bv[q] = *(const v4f*)(dbl + (size_t)t * 64 + DTR + q * 4);
            Cv[q] = *(const v4f*)(dbl + (size_t)t * 64 + DTR + DS + q * 4);
        }
        float du = dtv * uv;
        float y = 0.f;
#pragma unroll
        for (int s = 0; s < 16; ++s) {
            float dA = __expf(dtv * Ac[s]);
            h[s] = fmaf(dA, h[s], du * Bv[s >> 2][s & 3]);
            y = fmaf(h[s], Cv[s >> 2][s & 3], y);
        }
        int tp = perm[t];
        float z = xz[(size_t)tp * (2 * DI) + DI + c];
        float sig = 1.f / (1.f + __expf(-z));
        yo[(size_t)tp * DI + c] = (_Float16)((y + uv * Dp) * (z * sig));
    }
}

// ---------------- attention score: avec[t] = t1[t,:] . w2 + b2 ----------------
__global__ __launch_bounds__(256) void attnscore_k(
    const float* __restrict__ t1, const float* __restrict__ w2,
    const float* __restrict__ b2, float* __restrict__ avec)
{
    int t = blockIdx.x * 256 + threadIdx.x;
    const float* r = t1 + (size_t)t * 128;
    float acc = 0.f;
#pragma unroll 8
    for (int j = 0; j < 128; ++j) acc = fmaf(r[j], w2[j], acc);
    avec[t] = acc + b2[0];
}

// ---------------- softmax over 4096 (single block) ----------------
__global__ __launch_bounds__(1024) void softmax_k(
    const float* __restrict__ a, float* __restrict__ out)
{
    int tid = threadIdx.x;
    float v[4];
    float mx = -1e30f;
#pragma unroll
    for (int i = 0; i < 4; ++i) { v[i] = a[tid + i * 1024]; mx = fmaxf(mx, v[i]); }
    __shared__ float sm[16];
    for (int off = 32; off; off >>= 1) mx = fmaxf(mx, __shfl_xor(mx, off, 64));
    int wave = tid >> 6, lane = tid & 63;
    if (lane == 0) sm[wave] = mx;
    __syncthreads();
    if (tid < 16) {
        float m = sm[tid];
        for (int off = 8; off; off >>= 1) m = fmaxf(m, __shfl_xor(m, off, 64));
        sm[tid] = m;
    }
    __syncthreads();
    mx = sm[0];
    float s = 0.f;
#pragma unroll
    for (int i = 0; i < 4; ++i) { v[i] = __expf(v[i] - mx); s += v[i]; }
    for (int off = 32; off; off >>= 1) s += __shfl_xor(s, off, 64);
    __syncthreads();
    if (lane == 0) sm[wave] = s;
    __syncthreads();
    if (tid < 16) {
        float t2 = sm[tid];
        for (int off = 8; off; off >>= 1) t2 += __shfl_xor(t2, off, 64);
        sm[tid] = t2;
    }
    __syncthreads();
    float inv = 1.f / sm[0];
#pragma unroll
    for (int i = 0; i < 4; ++i) out[tid + i * 1024] = v[i] * inv;
}

__global__ void zero_k(float* p, int n) {
    int i = blockIdx.x * 256 + threadIdx.x;
    if (i < n) p[i] = 0.f;
}

__global__ __launch_bounds__(512) void pool_k(
    const float* __restrict__ aatt, const float* __restrict__ h,
    float* __restrict__ pooled)
{
    int m = threadIdx.x;
    int t0 = blockIdx.x * 128;
    float acc = 0.f;
    for (int r = 0; r < 128; ++r) {
        int t = t0 + r;
        acc = fmaf(aatt[t], h[(size_t)t * DM + m], acc);
    }
    atomicAdd(&pooled[m], acc);
}

__global__ __launch_bounds__(64) void out2048_k(
    const float* __restrict__ pooled, const float* __restrict__ w,
    const float* __restrict__ b, float* __restrict__ out)
{
    int n = blockIdx.x;
    int lane = threadIdx.x;
    const float* wr = w + (size_t)n * DM;
    float acc = 0.f;
#pragma unroll
    for (int k = 0; k < 8; ++k)
        acc = fmaf(wr[lane + k * 64], pooled[lane + k * 64], acc);
    for (int off = 32; off; off >>= 1) acc += __shfl_xor(acc, off, 64);
    if (lane == 0) out[n] = acc + b[n];
}

extern "C" void kernel_launch(void* const* d_in, const int* in_sizes, int n_in,
                              void* d_out, int out_size, void* d_ws, size_t ws_size,
                              hipStream_t stream) {
    const float* x     = (const float*)d_in[0];
    const int*   rate  = (const int*)d_in[1];
    const float* fc1_w = (const float*)d_in[2];
    const float* fc1_b = (const float*)d_in[3];
    const float* ln_w  = (const float*)d_in[4];
    const float* ln_b  = (const float*)d_in[5];
    const float* ipw   = (const float*)d_in[6];
    const float* cw    = (const float*)d_in[7];
    const float* cb    = (const float*)d_in[8];
    const float* xpw   = (const float*)d_in[9];
    const float* dtw   = (const float*)d_in[10];
    const float* dtpb  = (const float*)d_in[11];
    const float* A_log = (const float*)d_in[12];
    const float* Dsk   = (const float*)d_in[13];
    const float* opw   = (const float*)d_in[14];
    const float* nw    = (const float*)d_in[15];
    const float* nb    = (const float*)d_in[16];
    const float* aw1   = (const float*)d_in[17];
    const float* ab1   = (const float*)d_in[18];
    const float* aw2   = (const float*)d_in[19];
    const float* ab2   = (const float*)d_in[20];
    const float* ow    = (const float*)d_in[21];
    const float* ob    = (const float*)d_in[22];
    float* out = (float*)d_out;

    int* perm = (int*)d_ws;
    float* f = (float*)d_ws + 4096;
    float* h    = f; f += (size_t)L * DM;
    float* hln  = f; f += (size_t)L * DM;
    float* xz   = f; f += (size_t)L * 2 * DI;
    float* xc   = f; f += (size_t)L * DI;
    float* dbl  = f; f += (size_t)L * 64;
    float* dtv  = f; f += (size_t)L * DI;
    float* t1   = f; f += (size_t)L * 128;
    float* avec = f; f += L;
    float* pooled = f; f += DM;
    float* Aprod = f; f += (size_t)NCH * DI * DS;
    float* carry = f; f += (size_t)NCH * DI * DS;
    float* Hin   = f; f += (size_t)NCH * DI * DS;
    _Float16* fh = (_Float16*)f;
    _Float16* xh     = fh; fh += (size_t)L * DIN;
    _Float16* hln_h  = fh; fh += (size_t)L * DM;
    _Float16* yo_h   = fh; fh += (size_t)L * DI;
    _Float16* fc1w_h = fh; fh += (size_t)DM * DIN;
    _Float16* ipw_h  = fh; fh += (size_t)2 * 2 * DI * DM;
    _Float16* opw_h  = fh; fh += (size_t)2 * DM * DI;

    perm_k<<<16, 256, 0, stream>>>(perm, rate);

    // weight / input conversions to fp16 (cheap, memory-bound)
    f2h_k<<<L * DIN / 1024, 256, 0, stream>>>(x, xh);
    f2h_k<<<DM * DIN / 1024, 256, 0, stream>>>(fc1_w, fc1w_h);
    f2h_k<<<2 * 2 * DI * DM / 1024, 256, 0, stream>>>(ipw, ipw_h);
    f2h_k<<<2 * DM * DI / 1024, 256, 0, stream>>>(opw, opw_h);

    // h = relu(x @ fc1_w^T + fc1_b)   [fp16 MFMA, N64 tile -> 256 blocks]
    hgemm_nt<1, 64><<<dim3(DM / 64, L / 128), 256, 0, stream>>>(
        xh, DIN, fc1w_h, DIN, h, DM, fc1_b, DIN, 0);

    for (int l = 0; l < 2; ++l) {
        layernorm_k<<<L, 256, 0, stream>>>(h, ln_w + l * DM, ln_b + l * DM, hln, hln_h);
        // xz = hln @ in_proj^T   [fp16 MFMA, 128x128 tile -> 512 blocks]
        hgemm_nt<0, 128><<<dim3(2 * DI / 128, L / 128), 256, 0, stream>>>(
            hln_h, DM, ipw_h + (size_t)l * 2 * DI * DM, DM, xz, 2 * DI,
            nullptr, DM, 0);
        // xc = silu(causal_conv(x_perm))
        conv_silu_k<<<L * DI / 256, 256, 0, stream>>>(
            xz, perm, cw + (size_t)l * DI * 4, cb + (size_t)l * DI, xc);
        // dbl = xc @ x_proj^T  (N=64; split-K x4 for occupancy, atomic partials)
        zero4_k<<<L * 64 / 1024, 256, 0, stream>>>(dbl);
        gemm_nt<0><<<dim3(1, L / 64, 4), 256, 0, stream>>>(
            xc, DI, xpw + (size_t)l * 64 * DI, DI, dbl, 64, nullptr,
            L, 64, DI, DI / 4, 2);
        // dt = softplus(dbl[:, :32] @ dt_proj^T + dtb)  (K=32, fp32 SIMT)
        gemm_nt<2><<<dim3(DI / 64, L / 64), 256, 0, stream>>>(
            dbl, 64, dtw + (size_t)l * DI * DTR, DTR, dtv, DI,
            dtpb + (size_t)l * DI, L, DI, DTR, DTR, 0);
        // chunked parallel selective scan (channel-per-thread, states in regs)
        scan_pass1<<<dim3(DI / 256, NCH), 256, 0, stream>>>(
            dtv, xc, dbl, A_log + (size_t)l * DI * DS, Aprod, carry);
        scan_pass2<<<DI * DS / 256, 256, 0, stream>>>(Aprod, carry, Hin);
        scan_pass3<<<dim3(DI / 256, NCH), 256, 0, stream>>>(
            dtv, xc, dbl, xz, A_log + (size_t)l * DI * DS, Dsk + (size_t)l * DI,
            perm, Hin, yo_h);
        // h += yo @ out_proj^T   [fp16 MFMA, N64 tile -> 256 blocks, accumulate]
        hgemm_nt<0, 64><<<dim3(DM / 64, L / 128), 256, 0, stream>>>(
            yo_h, DI, opw_h + (size_t)l * DM * DI, DI, h, DM, nullptr, DI, 1);
    }

    layernorm_k<<<L, 256, 0, stream>>>(h, nw, nb, hln, nullptr);
    // t1 = tanh(hln @ aw1^T + ab1)  (fp32 SIMT)
    gemm_nt<3><<<dim3(128 / 64, L / 64), 256, 0, stream>>>(
        hln, DM, aw1, DM, t1, 128, ab1, L, 128, DM, DM, 0);
    attnscore_k<<<L / 256, 256, 0, stream>>>(t1, aw2, ab2, avec);
    softmax_k<<<1, 1024, 0, stream>>>(avec, out + 2048);
    zero_k<<<2, 256, 0, stream>>>(pooled, DM);
    pool_k<<<32, 512, 0, stream>>>(out + 2048, hln, pooled);
    out2048_k<<<2048, 64, 0, stream>>>(pooled, ow, ob, out);
}